// Round 10
// baseline (3590.667 us; speedup 1.0000x reference)
//
#include <hip/hip_runtime.h>
#include <stdint.h>

typedef __attribute__((ext_vector_type(8))) short short8;
typedef __attribute__((ext_vector_type(16))) float floatx16;

#define PLANE 16777216  // 8*256*256*32 elems: one 32-channel plane of an activation

__device__ __forceinline__ float b2f(short s) {
  union { uint32_t u; float f; } v; v.u = ((uint32_t)(uint16_t)s) << 16; return v.f;
}
__device__ __forceinline__ short f2b(float f) {
  union { float f; uint32_t u; } v; v.f = f;
  uint32_t r = (v.u + 0x7FFFu + ((v.u >> 16) & 1u)) >> 16;
  return (short)r;
}

// ROUND-10 LDS: two 33-KB buffers, each [4 rows][258 xp][16 ch] bf16
// (32 B per (r,xp) row). Swizzle XORs ONLY byte bit 4 (the 16-B half
// within a row) with g(xp) = xp2^xp3^xp4 -> injective by construction
// (half-swap inside the row), and spreads the 8 lanes sharing (xp0,xp1)
// across both 16-B bank slots (balanced 8 lanes / 4-bank group).
__device__ __forceinline__ uint32_t ldsA16(int buf, int r, int xp, int c) {
  uint32_t byte = (uint32_t)buf * 33024u + ((uint32_t)(r * 258 + xp) << 5)
                + ((uint32_t)c << 1);
  byte ^= (uint32_t)(((xp >> 2) ^ (xp >> 3) ^ (xp >> 4)) & 1) << 4;
  return byte;
}

// ---------------------------------------------------------------------------
// Main MFMA conv: 3x3, pad 1, C_in = 16*NC16 (16-ch chunks; chunks 0-3 from
// in1, 4-7 from in2), C_out = 64, PReLU.
// Activations: split-plane NHWC bf16 [plane][8][256][256][32].
// Block: 2 output rows, 512 threads = 8 waves: w&1 = y row, w>>1 = px quarter.
// Each wave: 2 mf (px) x 2 nblk (cout), acc 64 VGPR.
//
// ROUND-10 STRUCTURE (double-buffer, 1 barrier/chunk):
//   per chunk c: issue loads(c+1) -> compute c from buf[p] (9 taps, 36 MFMA)
//   -> commit(c+1) into buf[p^1] (other buffer: legal while others compute)
//   -> ONE __syncthreads. Removes R4's read-drain barrier before commit.
//
// TOOLCHAIN LAWS (r3/5/6): 1024-thr blocks force 64 VGPR -> spill; min-waves
// capping VGPR<130 -> spill; (512,2) safe. WRITE_SIZE>65.5MB = spill canary.
// R7/R9 LAW: added inner-loop VALU or loop reorders on the R4 structure
// regress; this round changes the structure itself instead.
// R9 FINDING: SQ_LDS_BANK_CONFLICT = 5767168 invariant across swizzles ->
// counter is write-phase-structural, not a lever.
//
// A-frag k-map (k = 8*(l>>5)+e, cin = c16*16+k) and B-pack share the same
// permutation (cancels).
// C/D: col(=cout_local)=lane&31, row(=px_local)=(r&3)+8*(r>>2)+4*(lane>>5)
// ---------------------------------------------------------------------------
template<int NC16>
__global__ __launch_bounds__(512, 2)
void k_conv(const short* __restrict__ in1, const short* __restrict__ in2,
            const short* __restrict__ wp, const float* __restrict__ bias,
            const float* __restrict__ alpha, short* __restrict__ out)
{
  __shared__ __align__(16) uint8_t smem[2 * 33024];
  const int y0 = blockIdx.x * 2, b = blockIdx.y;
  const int tid = threadIdx.x;
  const int l = tid & 63;
  const int w = tid >> 6;
  const int yrow = w & 1;
  const int pxq = w >> 1;
  const int lm = l & 31;
  const int lh = l >> 5;

  floatx16 acc[4];  // [mf][nblk] -> acc[mf*2+nblk]
  #pragma unroll
  for (int mf = 0; mf < 4; ++mf)
    #pragma unroll
    for (int r = 0; r < 16; ++r) acc[mf][r] = 0.f;

  const int xbase = pxq * 64 + lm;

  // staging: widx = tid + i*512 in [0,2048): r = widx>>9, xp = ((widx&511)>>1)+1,
  // half = widx&1. Exactly 4 16-B items/thread (pad columns excluded).
  short8 stg[4];

  auto issue = [&](int c16) {
    const short* __restrict__ src =
        ((c16 < 4) ? in1 : in2) + (size_t)((c16 >> 1) & 1) * PLANE;
    const int cb = (c16 & 1) * 16;
    #pragma unroll
    for (int i = 0; i < 4; ++i) {
      int widx = tid + i * 512;
      int r = widx >> 9;
      int rem = widx & 511;
      int xp = (rem >> 1) + 1;
      int half = rem & 1;
      int yy = y0 + r - 1;
      short8 v = {0, 0, 0, 0, 0, 0, 0, 0};
      if ((unsigned)yy < 256u)
        v = *(const short8*)(src + ((b * 256 + yy) * 256 + (xp - 1)) * 32 + cb + half * 8);
      stg[i] = v;
    }
  };
  auto commit = [&](int buf) {
    #pragma unroll
    for (int i = 0; i < 4; ++i) {
      int widx = tid + i * 512;
      int r = widx >> 9;
      int rem = widx & 511;
      int xp = (rem >> 1) + 1;
      int half = rem & 1;
      *(short8*)(smem + ldsA16(buf, r, xp, half * 8)) = stg[i];
    }
  };

  // zero the constant x-pad columns (xp=0,257) of BOTH buffers once; chunk
  // commits never touch them (swizzle stays within the row).
  if (tid < 32) {
    short8 z = {0, 0, 0, 0, 0, 0, 0, 0};
    int buf = tid >> 4;
    int r = (tid >> 2) & 3;
    int xp = (tid & 2) ? 257 : 0;
    int half = tid & 1;
    *(short8*)(smem + ldsA16(buf, r, xp, half * 8)) = z;
  }

  issue(0);
  commit(0);
  __syncthreads();

  #pragma unroll
  for (int c16 = 0; c16 < NC16; ++c16) {
    const int p = c16 & 1;
    if (c16 + 1 < NC16) issue(c16 + 1);   // loads fly under this chunk's MFMA

    #pragma unroll
    for (int ky = 0; ky < 3; ++ky)
    #pragma unroll
    for (int kx = 0; kx < 3; ++kx) {
      const int ks = c16 * 9 + ky * 3 + kx;
      const short8 bw0 = *(const short8*)(wp + ((ks * 2 + 0) * 64 + l) * 8);
      const short8 bw1 = *(const short8*)(wp + ((ks * 2 + 1) * 64 + l) * 8);
      const int cl = lh * 8;
      #pragma unroll
      for (int mf = 0; mf < 2; ++mf) {
        const int xp = xbase + mf * 32 + kx;
        const short8 av = *(const short8*)(smem + ldsA16(p, yrow + ky, xp, cl));
        acc[mf * 2 + 0] = __builtin_amdgcn_mfma_f32_32x32x16_bf16(av, bw0, acc[mf * 2 + 0], 0, 0, 0);
        acc[mf * 2 + 1] = __builtin_amdgcn_mfma_f32_32x32x16_bf16(av, bw1, acc[mf * 2 + 1], 0, 0, 0);
      }
    }

    if (c16 + 1 < NC16) {
      commit(p ^ 1);       // other buffer: no read-drain barrier needed
      __syncthreads();     // one barrier per chunk
    }
  }

  const float alp = alpha[0];
  const int y = y0 + yrow;
  #pragma unroll
  for (int nb = 0; nb < 2; ++nb) {
    const float bs = bias[nb * 32 + lm];
    short* __restrict__ op = out + (size_t)nb * PLANE + lm;
    #pragma unroll
    for (int mf = 0; mf < 2; ++mf) {
      #pragma unroll
      for (int r = 0; r < 16; ++r) {
        int px = pxq * 64 + mf * 32 + (r & 3) + ((r >> 2) << 3) + (lh << 2);
        float v = acc[mf * 2 + nb][r] + bs;
        v = v >= 0.f ? v : alp * v;
        op[((b * 256 + y) * 256 + px) * 32] = f2b(v);
      }
    }
  }
}

// ---------------------------------------------------------------------------
// Weight pre-pack, (q,s)-major: ks16 = (q*2+s)*9 + tap (= c16*9 + tap).
// element (ks16, nblk, lane, e) =
//   W[cout = nblk*32 + lane&31][cin = c16*16 + 8*(lane>>5) + e][ky][kx]
// ---------------------------------------------------------------------------
__global__ __launch_bounds__(256)
void k_pack(const float* __restrict__ w2, const float* __restrict__ w3,
            const float* __restrict__ w4, const float* __restrict__ wf,
            short* __restrict__ wp234, short* __restrict__ wpfus)
{
  int idx = blockIdx.x * 256 + threadIdx.x;
  if (idx < 24 * 36864) {
    int conv = idx / 36864;
    int r = idx - conv * 36864;
    int which = conv >> 3, g = conv & 7;
    const float* W = (which == 0 ? w2 : which == 1 ? w3 : w4) + g * 36864;
    int ks = r >> 10;                 // [0,36) = c16*9 + t
    int nblk = (r >> 9) & 1;
    int lane = (r >> 3) & 63;
    int e = r & 7;
    int c16 = ks / 9;
    int t = ks - c16 * 9;
    int cin = c16 * 16 + ((lane >> 5) << 3) + e;
    int cout = nblk * 32 + (lane & 31);
    int ky = t / 3, kx = t % 3;
    wp234[idx] = f2b(W[((cout * 64 + cin) * 3 + ky) * 3 + kx]);
  } else {
    int idx2 = idx - 24 * 36864;
    if (idx2 >= 7 * 73728) return;
    int conv = idx2 / 73728;
    int r = idx2 - conv * 73728;
    const float* W = wf + conv * 73728;
    int ks = r >> 10;                 // [0,72)
    int nblk = (r >> 9) & 1;
    int lane = (r >> 3) & 63;
    int e = r & 7;
    int c16 = ks / 9;
    int t = ks - c16 * 9;
    int cin = c16 * 16 + ((lane >> 5) << 3) + e;
    int cout = nblk * 32 + (lane & 31);
    int ky = t / 3, kx = t % 3;
    wpfus[idx2] = f2b(W[((cout * 128 + cin) * 3 + ky) * 3 + kx]);
  }
}

// ---------------------------------------------------------------------------
// Head stage 1: sample conv (32x32, stride 32). s_all[g][b][c][gy][gx], fp32.
// ---------------------------------------------------------------------------
__global__ __launch_bounds__(256)
void k_sample(const float* __restrict__ x, const float* __restrict__ sw,
              float* __restrict__ s_all)
{
  int idx = blockIdx.x * 256 + threadIdx.x;  // 8*8*13*64 = 53248 threads
  int gx = idx & 7, gy = (idx >> 3) & 7;
  int t = idx >> 6;
  int c = t % 13; t /= 13;
  int b = t & 7, g = t >> 3;
  const float* xb = x + b * 65536 + (gy * 32) * 256 + gx * 32;
  const float* wp = sw + (g * 13 + c) * 1024;
  float acc = 0.f;
  for (int i = 0; i < 32; ++i) {
    #pragma unroll
    for (int j = 0; j < 32; ++j) acc += xb[i * 256 + j] * wp[i * 32 + j];
  }
  s_all[idx] = acc;
}

// ---------------------------------------------------------------------------
// Head stage 2: 1x1 up conv + bias, fused with depth_to_space.
// z_all[g][b][y][x] fp32, pos = (y%32)*32 + (x%32).
// ---------------------------------------------------------------------------
__global__ __launch_bounds__(256)
void k_upz(const float* __restrict__ s_all, const float* __restrict__ upw,
           const float* __restrict__ upb, float* __restrict__ z_all)
{
  int idx = blockIdx.x * 256 + threadIdx.x;  // 4194304
  int x = idx & 255, y = (idx >> 8) & 255;
  int b = (idx >> 16) & 7, g = idx >> 19;
  int pos = (y & 31) * 32 + (x & 31);
  int gy = y >> 5, gx = x >> 5;
  const float* sp = s_all + ((g * 8 + b) * 13) * 64 + gy * 8 + gx;
  const float* wp = upw + (g * 1024 + pos) * 13;
  float a = upb[g * 1024 + pos];
  #pragma unroll
  for (int c = 0; c < 13; ++c) a += wp[c] * sp[c * 64];
  z_all[idx] = a;
}

// ---------------------------------------------------------------------------
// Head stage 3: conv1 (1 -> 64, 3x3, pad 1) + PReLU, writes split-plane bf16.
// ---------------------------------------------------------------------------
__global__ __launch_bounds__(256)
void k_conv1(const float* __restrict__ z, const float* __restrict__ w,
             const float* __restrict__ bias, const float* __restrict__ alpha,
             short* __restrict__ out)
{
  int pid = blockIdx.x * 256 + threadIdx.x;  // b*65536 + y*256 + x
  int x = pid & 255, y = (pid >> 8) & 255, b = pid >> 16;
  float zv[9];
  #pragma unroll
  for (int t = 0; t < 9; ++t) {
    int dy = t / 3, dx = t % 3;
    int yy = y + dy - 1, xx = x + dx - 1;
    zv[t] = ((unsigned)yy < 256u && (unsigned)xx < 256u)
              ? z[b * 65536 + yy * 256 + xx] : 0.f;
  }
  float alp = alpha[0];
  #pragma unroll
  for (int c0 = 0; c0 < 64; c0 += 8) {
    short8 pack;
    #pragma unroll
    for (int e = 0; e < 8; ++e) {
      int c = c0 + e;
      float a = bias[c];
      #pragma unroll
      for (int t = 0; t < 9; ++t) a += w[c * 9 + t] * zv[t];
      a = a >= 0.f ? a : alp * a;
      pack[e] = f2b(a);
    }
    *(short8*)(out + (size_t)(c0 >> 5) * PLANE + pid * 32 + (c0 & 31)) = pack;
  }
}

// ---------------------------------------------------------------------------
// t5: 64 -> 1, 3x3, pad 1, + bias, fp32 output into d_out slice.
// ---------------------------------------------------------------------------
__global__ __launch_bounds__(256)
void k_t5(const short* __restrict__ in, const float* __restrict__ w,
          const float* __restrict__ bias, float* __restrict__ out)
{
  int pid = blockIdx.x * 256 + threadIdx.x;
  int x = pid & 255, y = (pid >> 8) & 255, b = pid >> 16;
  float acc = bias[0];
  for (int dy = 0; dy < 3; ++dy) {
    int yy = y + dy - 1;
    if ((unsigned)yy >= 256u) continue;
    for (int dx = 0; dx < 3; ++dx) {
      int xx = x + dx - 1;
      if ((unsigned)xx >= 256u) continue;
      const int pix = (b * 256 + yy) * 256 + xx;
      #pragma unroll
      for (int c0 = 0; c0 < 64; c0 += 8) {
        short8 v = *(const short8*)(in + (size_t)(c0 >> 5) * PLANE + pix * 32 + (c0 & 31));
        #pragma unroll
        for (int e = 0; e < 8; ++e)
          acc += w[(c0 + e) * 9 + dy * 3 + dx] * b2f(v[e]);
      }
    }
  }
  out[pid] = acc;
}

// ---------------------------------------------------------------------------
extern "C" void kernel_launch(void* const* d_in, const int* in_sizes, int n_in,
                              void* d_out, int out_size, void* d_ws, size_t ws_size,
                              hipStream_t stream) {
  const float* X   = (const float*)d_in[0];
  const float* SW  = (const float*)d_in[1];
  const float* UPW = (const float*)d_in[2];
  const float* UPB = (const float*)d_in[3];
  const float* C1W = (const float*)d_in[4];
  const float* C1B = (const float*)d_in[5];
  const float* C1A = (const float*)d_in[6];
  const float* FW  = (const float*)d_in[7];
  const float* FB  = (const float*)d_in[8];
  const float* FA  = (const float*)d_in[9];
  const float* W2  = (const float*)d_in[10];
  const float* B2  = (const float*)d_in[11];
  const float* A2  = (const float*)d_in[12];
  const float* W3  = (const float*)d_in[13];
  const float* B3  = (const float*)d_in[14];
  const float* A3  = (const float*)d_in[15];
  const float* W4  = (const float*)d_in[16];
  const float* B4  = (const float*)d_in[17];
  const float* A4  = (const float*)d_in[18];
  const float* W5  = (const float*)d_in[19];
  const float* B5  = (const float*)d_in[20];
  float* OUT = (float*)d_out;
  (void)in_sizes; (void)n_in; (void)out_size; (void)ws_size;

  uint8_t* base = (uint8_t*)d_ws;
  size_t off = 0;
  auto alloc = [&](size_t bytes) -> uint8_t* {
    uint8_t* r = base + off;
    off += (bytes + 255) & ~(size_t)255;
    return r;
  };
  const size_t ACT_ELEMS = 2ull * PLANE;               // 33,554,432 bf16
  short* act[3];
  for (int i = 0; i < 3; ++i) act[i] = (short*)alloc(ACT_ELEMS * 2);
  float* z_all = (float*)alloc(4194304ull * 4);
  float* s_all = (float*)alloc(53248ull * 4);
  short* wp234 = (short*)alloc(884736ull * 2);
  short* wpfus = (short*)alloc(516096ull * 2);

  k_pack<<<dim3(5472), dim3(256), 0, stream>>>(W2, W3, W4, FW, wp234, wpfus);
  k_sample<<<dim3(208), dim3(256), 0, stream>>>(X, SW, s_all);
  k_upz<<<dim3(16384), dim3(256), 0, stream>>>(s_all, UPW, UPB, z_all);

  int cur = 0, A = 1, B = 2;
  // head(0) -> cur
  k_conv1<<<dim3(2048), dim3(256), 0, stream>>>(z_all, C1W, C1B, C1A, act[cur]);

  for (int m = 0; m < 8; ++m) {
    const short* wp_t2 = wp234 + (0 * 8 + m) * 36864;
    const short* wp_t3 = wp234 + (1 * 8 + m) * 36864;
    const short* wp_t4 = wp234 + (2 * 8 + m) * 36864;

    k_conv<4><<<dim3(128, 8), dim3(512), 0, stream>>>(
        act[cur], act[cur], wp_t2, B2 + m * 64, A2 + m, act[A]);
    k_conv<4><<<dim3(128, 8), dim3(512), 0, stream>>>(
        act[A], act[A], wp_t3, B3 + m * 64, A3 + m, act[B]);
    k_conv<4><<<dim3(128, 8), dim3(512), 0, stream>>>(
        act[B], act[B], wp_t4, B4 + m * 64, A4 + m, act[A]);
    k_t5<<<dim3(2048), dim3(256), 0, stream>>>(
        act[A], W5 + m * 576, B5 + m, OUT + (size_t)m * 524288);

    if (m < 7) {
      // head(m+1) -> act[B] (free after t4 consumed it)
      k_conv1<<<dim3(2048), dim3(256), 0, stream>>>(
          z_all + (size_t)(m + 1) * 524288, C1W + (m + 1) * 576,
          C1B + (m + 1) * 64, C1A + (m + 1), act[B]);
      // fus(cur, head) -> act[A] (free after t5 consumed it)
      k_conv<8><<<dim3(128, 8), dim3(512), 0, stream>>>(
          act[cur], act[B], wpfus + m * 73728, FB + m * 64, FA + m, act[A]);
      int tmp = cur; cur = A; A = tmp;  // new cur = fus output
    }
  }
}

// Round 11
// 3439.205 us; speedup vs baseline: 1.0440x; 1.0440x over previous
//
#include <hip/hip_runtime.h>
#include <stdint.h>

typedef __attribute__((ext_vector_type(8))) short short8;
typedef __attribute__((ext_vector_type(16))) float floatx16;

#define PLANE 16777216  // 8*256*256*32 elems: one 32-channel plane of an activation

__device__ __forceinline__ float b2f(short s) {
  union { uint32_t u; float f; } v; v.u = ((uint32_t)(uint16_t)s) << 16; return v.f;
}
__device__ __forceinline__ short f2b(float f) {
  union { float f; uint32_t u; } v; v.f = f;
  uint32_t r = (v.u + 0x7FFFu + ((v.u >> 16) & 1u)) >> 16;
  return (short)r;
}

// LDS tile: [4 rows][258 xp][32 c] bf16, 64 B per (r,xp) row, XOR-swizzled.
// R4 formula, validated. Used for staging/commit/pad; the MFMA read path
// uses the hoisted-XOR factorization below (bit-identical, see k_conv).
__device__ __forceinline__ uint32_t ldsAddr(int r, int xp, int c) {
  uint32_t byte = ((uint32_t)(r * 258 + xp) << 6) + ((uint32_t)c << 1);
  byte ^= ((uint32_t)(xp & 7)) << 4;
  return byte;
}

// ---------------------------------------------------------------------------
// Main MFMA conv: 3x3, pad 1, C_in = 32*NCHUNK (chunks 0,1 = planes of in1,
// chunks 2,3 = planes of in2), C_out = 64, PReLU.
// Activations: split-plane NHWC bf16 [plane][8][256][256][32].
// Block: 2 output rows (b, y0=2*blockIdx.x), 512 threads = 8 waves:
//   w&1 = y row, w>>1 = px quarter. Each wave: 2 mf (px) x 2 nblk (cout).
// T14 async-stage: issue chunk q+1 global loads before computing chunk q.
//
// TOOLCHAIN LAWS (r3/5/6): 1024-thr blocks force 64 VGPR -> spill; min-waves
// capping VGPR<130 -> spill; (512,2) -> 114 VGPR safe. WRITE_SIZE>65.5MB =
// spill canary. VGPR must stay <=128 for 4 waves/SIMD.
// CRITICAL-PATH LAW (r7/r9/r10): the kernel is issue-bound on the
// ds_read->MFMA chain; every extra VALU op per LDS read costs ~2x (r9).
// Bank conflicts (counter invariant 5.77M) and HBM BW (r8) are NOT levers.
//
// ROUND-11 CHANGE: hoist LDS read addresses. Address algebra:
//   true addr = rowlin(yrow+ky,xp) + (s*32+lh*16) ^ ((xp&7)<<4)
// rowlin bits >=6, c-term bits 4-5, mask bits 4-6, ky-term bits 0-6 zero
// => addr == (rowlin(yrow,xp) ^ mask ^ lh*16) ^ (s<<5) + ky*16512.
// Precompute aof[mf][kx] (6 wave-constant VGPRs) once; inner reads become
// ds_read at reg (+1 v_xor for s=1) + immediate. Zero other changes vs R4.
//
// A-frag k-map and B-frag pack share the same k-permutation (cancels).
// C/D: col(=cout_local)=lane&31, row(=px_local)=(r&3)+8*(r>>2)+4*(lane>>5)
// ---------------------------------------------------------------------------
template<int NCHUNK>
__global__ __launch_bounds__(512, 2)
void k_conv(const short* __restrict__ in1, const short* __restrict__ in2,
            const short* __restrict__ wp, const float* __restrict__ bias,
            const float* __restrict__ alpha, short* __restrict__ out)
{
  __shared__ __align__(16) uint8_t smem[4 * 258 * 64];
  const int y0 = blockIdx.x * 2, b = blockIdx.y;
  const int tid = threadIdx.x;
  const int l = tid & 63;
  const int w = tid >> 6;
  const int yrow = w & 1;
  const int pxq = w >> 1;
  const int lm = l & 31;
  const int lh = l >> 5;

  floatx16 acc[4];  // [mf][nblk] -> acc[mf*2+nblk]
  #pragma unroll
  for (int mf = 0; mf < 4; ++mf)
    #pragma unroll
    for (int r = 0; r < 16; ++r) acc[mf][r] = 0.f;

  const int xbase = pxq * 64 + lm;

  // Hoisted A-read offsets (wave-constant): see derivation in header comment.
  uint32_t aof[2][3];
  #pragma unroll
  for (int mf = 0; mf < 2; ++mf)
    #pragma unroll
    for (int kx = 0; kx < 3; ++kx) {
      const int xp = xbase + mf * 32 + kx;
      aof[mf][kx] = (((uint32_t)(yrow * 258 + xp)) << 6)
                  ^ (((uint32_t)(xp & 7)) << 4)
                  ^ ((uint32_t)lh << 4);
    }

  // staging: widx = tid + i*512, i in 0..7 -> (r 0..3, xp in 1..256, co)
  short8 stg[8];

  auto issue = [&](int q) {
    const short* __restrict__ src = ((q < 2) ? in1 : in2) + (size_t)(q & 1) * PLANE;
    #pragma unroll
    for (int i = 0; i < 8; ++i) {
      int widx = tid + i * 512;
      int r = widx >> 10;
      int xp = ((widx >> 2) & 255) + 1;
      int co = (widx & 3) << 3;
      int yy = y0 + r - 1;
      short8 v = {0, 0, 0, 0, 0, 0, 0, 0};
      if ((unsigned)yy < 256u)
        v = *(const short8*)(src + ((b * 256 + yy) * 256 + (xp - 1)) * 32 + co);
      stg[i] = v;
    }
  };
  auto commit = [&]() {
    #pragma unroll
    for (int i = 0; i < 8; ++i) {
      int widx = tid + i * 512;
      int r = widx >> 10;
      int xp = ((widx >> 2) & 255) + 1;
      int co = (widx & 3) << 3;
      *(short8*)(smem + ldsAddr(r, xp, co)) = stg[i];
    }
  };

  // zero the constant x-pad columns (xp=0, 257) once; chunk writes never
  // touch these bytes (ldsAddr is injective).
  if (tid < 32) {
    short8 z = {0, 0, 0, 0, 0, 0, 0, 0};
    int r = tid >> 3;
    int xp = (tid & 4) ? 257 : 0;
    int co = (tid & 3) << 3;
    *(short8*)(smem + ldsAddr(r, xp, co)) = z;
  }

  issue(0);
  commit();
  __syncthreads();

  #pragma unroll
  for (int q = 0; q < NCHUNK; ++q) {
    if (q + 1 < NCHUNK) issue(q + 1);   // loads fly under the MFMA phase

    #pragma unroll
    for (int ky = 0; ky < 3; ++ky)
    #pragma unroll
    for (int kx = 0; kx < 3; ++kx)
    #pragma unroll
    for (int s = 0; s < 2; ++s) {
      const int ks = (q * 9 + ky * 3 + kx) * 2 + s;
      const short8 bw0 = *(const short8*)(wp + ((ks * 2 + 0) * 64 + l) * 8);
      const short8 bw1 = *(const short8*)(wp + ((ks * 2 + 1) * 64 + l) * 8);
      #pragma unroll
      for (int mf = 0; mf < 2; ++mf) {
        const short8 av = *(const short8*)(
            smem + ((aof[mf][kx] ^ (uint32_t)(s << 5)) + (uint32_t)(ky * 16512)));
        acc[mf * 2 + 0] = __builtin_amdgcn_mfma_f32_32x32x16_bf16(av, bw0, acc[mf * 2 + 0], 0, 0, 0);
        acc[mf * 2 + 1] = __builtin_amdgcn_mfma_f32_32x32x16_bf16(av, bw1, acc[mf * 2 + 1], 0, 0, 0);
      }
    }

    if (q + 1 < NCHUNK) {
      __syncthreads();   // all waves done reading LDS chunk q
      commit();
      __syncthreads();   // chunk q+1 visible
    }
  }

  const float alp = alpha[0];
  const int y = y0 + yrow;
  #pragma unroll
  for (int nb = 0; nb < 2; ++nb) {
    const float bs = bias[nb * 32 + lm];
    short* __restrict__ op = out + (size_t)nb * PLANE + lm;
    #pragma unroll
    for (int mf = 0; mf < 2; ++mf) {
      #pragma unroll
      for (int r = 0; r < 16; ++r) {
        int px = pxq * 64 + mf * 32 + (r & 3) + ((r >> 2) << 3) + (lh << 2);
        float v = acc[mf * 2 + nb][r] + bs;
        v = v >= 0.f ? v : alp * v;
        op[((b * 256 + y) * 256 + px) * 32] = f2b(v);
      }
    }
  }
}

// ---------------------------------------------------------------------------
// Weight pre-pack (R4 order: ks = (q*9 + tap)*2 + s).
// element (ks, nblk, lane, e) = W[cout = nblk*32 + lane&31][cin = q*32 + s*16 + 8*(lane>>5) + e]
// ---------------------------------------------------------------------------
__global__ __launch_bounds__(256)
void k_pack(const float* __restrict__ w2, const float* __restrict__ w3,
            const float* __restrict__ w4, const float* __restrict__ wf,
            short* __restrict__ wp234, short* __restrict__ wpfus)
{
  int idx = blockIdx.x * 256 + threadIdx.x;
  if (idx < 24 * 36864) {
    int conv = idx / 36864;
    int r = idx - conv * 36864;
    int which = conv >> 3, g = conv & 7;
    const float* W = (which == 0 ? w2 : which == 1 ? w3 : w4) + g * 36864;
    int ks = r >> 10;
    int nblk = (r >> 9) & 1;
    int lane = (r >> 3) & 63;
    int e = r & 7;
    int q = ks / 18, tt = ks % 18;
    int t = tt >> 1, s = tt & 1;
    int cin = q * 32 + s * 16 + ((lane >> 5) << 3) + e;
    int cout = nblk * 32 + (lane & 31);
    int ky = t / 3, kx = t % 3;
    wp234[idx] = f2b(W[((cout * 64 + cin) * 3 + ky) * 3 + kx]);
  } else {
    int idx2 = idx - 24 * 36864;
    if (idx2 >= 7 * 73728) return;
    int conv = idx2 / 73728;
    int r = idx2 - conv * 73728;
    const float* W = wf + conv * 73728;
    int ks = r >> 10;
    int nblk = (r >> 9) & 1;
    int lane = (r >> 3) & 63;
    int e = r & 7;
    int q = ks / 18, tt = ks % 18;
    int t = tt >> 1, s = tt & 1;
    int cin = q * 32 + s * 16 + ((lane >> 5) << 3) + e;
    int cout = nblk * 32 + (lane & 31);
    int ky = t / 3, kx = t % 3;
    wpfus[idx2] = f2b(W[((cout * 128 + cin) * 3 + ky) * 3 + kx]);
  }
}

// ---------------------------------------------------------------------------
// Head stage 1: sample conv (32x32, stride 32). s_all[g][b][c][gy][gx], fp32.
// ---------------------------------------------------------------------------
__global__ __launch_bounds__(256)
void k_sample(const float* __restrict__ x, const float* __restrict__ sw,
              float* __restrict__ s_all)
{
  int idx = blockIdx.x * 256 + threadIdx.x;  // 8*8*13*64 = 53248 threads
  int gx = idx & 7, gy = (idx >> 3) & 7;
  int t = idx >> 6;
  int c = t % 13; t /= 13;
  int b = t & 7, g = t >> 3;
  const float* xb = x + b * 65536 + (gy * 32) * 256 + gx * 32;
  const float* wp = sw + (g * 13 + c) * 1024;
  float acc = 0.f;
  for (int i = 0; i < 32; ++i) {
    #pragma unroll
    for (int j = 0; j < 32; ++j) acc += xb[i * 256 + j] * wp[i * 32 + j];
  }
  s_all[idx] = acc;
}

// ---------------------------------------------------------------------------
// Head stage 2: 1x1 up conv + bias, fused with depth_to_space.
// z_all[g][b][y][x] fp32, pos = (y%32)*32 + (x%32).
// ---------------------------------------------------------------------------
__global__ __launch_bounds__(256)
void k_upz(const float* __restrict__ s_all, const float* __restrict__ upw,
           const float* __restrict__ upb, float* __restrict__ z_all)
{
  int idx = blockIdx.x * 256 + threadIdx.x;  // 4194304
  int x = idx & 255, y = (idx >> 8) & 255;
  int b = (idx >> 16) & 7, g = idx >> 19;
  int pos = (y & 31) * 32 + (x & 31);
  int gy = y >> 5, gx = x >> 5;
  const float* sp = s_all + ((g * 8 + b) * 13) * 64 + gy * 8 + gx;
  const float* wp = upw + (g * 1024 + pos) * 13;
  float a = upb[g * 1024 + pos];
  #pragma unroll
  for (int c = 0; c < 13; ++c) a += wp[c] * sp[c * 64];
  z_all[idx] = a;
}

// ---------------------------------------------------------------------------
// Head stage 3: conv1 (1 -> 64, 3x3, pad 1) + PReLU, writes split-plane bf16.
// ---------------------------------------------------------------------------
__global__ __launch_bounds__(256)
void k_conv1(const float* __restrict__ z, const float* __restrict__ w,
             const float* __restrict__ bias, const float* __restrict__ alpha,
             short* __restrict__ out)
{
  int pid = blockIdx.x * 256 + threadIdx.x;  // b*65536 + y*256 + x
  int x = pid & 255, y = (pid >> 8) & 255, b = pid >> 16;
  float zv[9];
  #pragma unroll
  for (int t = 0; t < 9; ++t) {
    int dy = t / 3, dx = t % 3;
    int yy = y + dy - 1, xx = x + dx - 1;
    zv[t] = ((unsigned)yy < 256u && (unsigned)xx < 256u)
              ? z[b * 65536 + yy * 256 + xx] : 0.f;
  }
  float alp = alpha[0];
  #pragma unroll
  for (int c0 = 0; c0 < 64; c0 += 8) {
    short8 pack;
    #pragma unroll
    for (int e = 0; e < 8; ++e) {
      int c = c0 + e;
      float a = bias[c];
      #pragma unroll
      for (int t = 0; t < 9; ++t) a += w[c * 9 + t] * zv[t];
      a = a >= 0.f ? a : alp * a;
      pack[e] = f2b(a);
    }
    *(short8*)(out + (size_t)(c0 >> 5) * PLANE + pid * 32 + (c0 & 31)) = pack;
  }
}

// ---------------------------------------------------------------------------
// t5: 64 -> 1, 3x3, pad 1, + bias, fp32 output into d_out slice.
// ---------------------------------------------------------------------------
__global__ __launch_bounds__(256)
void k_t5(const short* __restrict__ in, const float* __restrict__ w,
          const float* __restrict__ bias, float* __restrict__ out)
{
  int pid = blockIdx.x * 256 + threadIdx.x;
  int x = pid & 255, y = (pid >> 8) & 255, b = pid >> 16;
  float acc = bias[0];
  for (int dy = 0; dy < 3; ++dy) {
    int yy = y + dy - 1;
    if ((unsigned)yy >= 256u) continue;
    for (int dx = 0; dx < 3; ++dx) {
      int xx = x + dx - 1;
      if ((unsigned)xx >= 256u) continue;
      const int pix = (b * 256 + yy) * 256 + xx;
      #pragma unroll
      for (int c0 = 0; c0 < 64; c0 += 8) {
        short8 v = *(const short8*)(in + (size_t)(c0 >> 5) * PLANE + pix * 32 + (c0 & 31));
        #pragma unroll
        for (int e = 0; e < 8; ++e)
          acc += w[(c0 + e) * 9 + dy * 3 + dx] * b2f(v[e]);
      }
    }
  }
  out[pid] = acc;
}

// ---------------------------------------------------------------------------
extern "C" void kernel_launch(void* const* d_in, const int* in_sizes, int n_in,
                              void* d_out, int out_size, void* d_ws, size_t ws_size,
                              hipStream_t stream) {
  const float* X   = (const float*)d_in[0];
  const float* SW  = (const float*)d_in[1];
  const float* UPW = (const float*)d_in[2];
  const float* UPB = (const float*)d_in[3];
  const float* C1W = (const float*)d_in[4];
  const float* C1B = (const float*)d_in[5];
  const float* C1A = (const float*)d_in[6];
  const float* FW  = (const float*)d_in[7];
  const float* FB  = (const float*)d_in[8];
  const float* FA  = (const float*)d_in[9];
  const float* W2  = (const float*)d_in[10];
  const float* B2  = (const float*)d_in[11];
  const float* A2  = (const float*)d_in[12];
  const float* W3  = (const float*)d_in[13];
  const float* B3  = (const float*)d_in[14];
  const float* A3  = (const float*)d_in[15];
  const float* W4  = (const float*)d_in[16];
  const float* B4  = (const float*)d_in[17];
  const float* A4  = (const float*)d_in[18];
  const float* W5  = (const float*)d_in[19];
  const float* B5  = (const float*)d_in[20];
  float* OUT = (float*)d_out;
  (void)in_sizes; (void)n_in; (void)out_size; (void)ws_size;

  uint8_t* base = (uint8_t*)d_ws;
  size_t off = 0;
  auto alloc = [&](size_t bytes) -> uint8_t* {
    uint8_t* r = base + off;
    off += (bytes + 255) & ~(size_t)255;
    return r;
  };
  const size_t ACT_ELEMS = 2ull * PLANE;               // 33,554,432 bf16
  short* act[3];
  for (int i = 0; i < 3; ++i) act[i] = (short*)alloc(ACT_ELEMS * 2);
  float* z_all = (float*)alloc(4194304ull * 4);
  float* s_all = (float*)alloc(53248ull * 4);
  short* wp234 = (short*)alloc(884736ull * 2);
  short* wpfus = (short*)alloc(516096ull * 2);

  k_pack<<<dim3(5472), dim3(256), 0, stream>>>(W2, W3, W4, FW, wp234, wpfus);
  k_sample<<<dim3(208), dim3(256), 0, stream>>>(X, SW, s_all);
  k_upz<<<dim3(16384), dim3(256), 0, stream>>>(s_all, UPW, UPB, z_all);

  int cur = 0, A = 1, B = 2;
  // head(0) -> cur
  k_conv1<<<dim3(2048), dim3(256), 0, stream>>>(z_all, C1W, C1B, C1A, act[cur]);

  for (int m = 0; m < 8; ++m) {
    const short* wp_t2 = wp234 + (0 * 8 + m) * 36864;
    const short* wp_t3 = wp234 + (1 * 8 + m) * 36864;
    const short* wp_t4 = wp234 + (2 * 8 + m) * 36864;

    k_conv<2><<<dim3(128, 8), dim3(512), 0, stream>>>(
        act[cur], act[cur], wp_t2, B2 + m * 64, A2 + m, act[A]);
    k_conv<2><<<dim3(128, 8), dim3(512), 0, stream>>>(
        act[A], act[A], wp_t3, B3 + m * 64, A3 + m, act[B]);
    k_conv<2><<<dim3(128, 8), dim3(512), 0, stream>>>(
        act[B], act[B], wp_t4, B4 + m * 64, A4 + m, act[A]);
    k_t5<<<dim3(2048), dim3(256), 0, stream>>>(
        act[A], W5 + m * 576, B5 + m, OUT + (size_t)m * 524288);

    if (m < 7) {
      // head(m+1) -> act[B] (free after t4 consumed it)
      k_conv1<<<dim3(2048), dim3(256), 0, stream>>>(
          z_all + (size_t)(m + 1) * 524288, C1W + (m + 1) * 576,
          C1B + (m + 1) * 64, C1A + (m + 1), act[B]);
      // fus(cur, head) -> act[A] (free after t5 consumed it)
      k_conv<4><<<dim3(128, 8), dim3(512), 0, stream>>>(
          act[cur], act[B], wpfus + m * 73728, FB + m * 64, FA + m, act[A]);
      int tmp = cur; cur = A; A = tmp;  // new cur = fus output
    }
  }
}

// Round 12
// 3420.283 us; speedup vs baseline: 1.0498x; 1.0055x over previous
//
#include <hip/hip_runtime.h>
#include <stdint.h>

typedef __attribute__((ext_vector_type(8))) short short8;
typedef __attribute__((ext_vector_type(16))) float floatx16;

#define PLANE 16777216  // 8*256*256*32 elems: one 32-channel plane of an activation

__device__ __forceinline__ float b2f(short s) {
  union { uint32_t u; float f; } v; v.u = ((uint32_t)(uint16_t)s) << 16; return v.f;
}
__device__ __forceinline__ short f2b(float f) {
  union { float f; uint32_t u; } v; v.f = f;
  uint32_t r = (v.u + 0x7FFFu + ((v.u >> 16) & 1u)) >> 16;
  return (short)r;
}

// LDS tile: [4 rows][258 xp][32 c] bf16, 64 B per (r,xp) row, XOR-swizzled.
// Same formula on write & read; injective (validated rounds 1-2).
__device__ __forceinline__ uint32_t ldsAddr(int r, int xp, int c) {
  uint32_t byte = ((uint32_t)(r * 258 + xp) << 6) + ((uint32_t)c << 1);
  byte ^= ((uint32_t)(xp & 7)) << 4;
  return byte;
}

// ---------------------------------------------------------------------------
// Main MFMA conv: 3x3, pad 1, C_in = 32*NCHUNK (chunks 0,1 = planes of in1,
// chunks 2,3 = planes of in2), C_out = 64, PReLU.
// Activations: split-plane NHWC bf16 [plane][8][256][256][32].
// Block: 2 output rows (b, y0=2*blockIdx.x), 512 threads = 8 waves:
//   w&1 = y row, w>>1 = px quarter. Each wave: 2 mf (px) x 2 nblk (cout).
// Pipelining: issue chunk q+1 global loads -> regs before computing chunk q
// (T14 async-stage); commit regs -> LDS after the post-compute barrier.
// NOTE round-3 lesson: __launch_bounds__ min-waves=4 forced VGPR<=64 and
// spilled the 32-VGPR staging block to scratch (+300 MB HBM). LDS already
// limits to 2 blocks/CU, so declare (512, 2) and keep stg in registers.
// A-frag k-map and B-frag pack share the same k-permutation (cancels).
// C/D: col(=cout_local)=lane&31, row(=px_local)=(r&3)+8*(r>>2)+4*(lane>>5)
// ---------------------------------------------------------------------------
template<int NCHUNK>
__global__ __launch_bounds__(512, 2)
void k_conv(const short* __restrict__ in1, const short* __restrict__ in2,
            const short* __restrict__ wp, const float* __restrict__ bias,
            const float* __restrict__ alpha, short* __restrict__ out)
{
  __shared__ __align__(16) uint8_t smem[4 * 258 * 64];
  const int y0 = blockIdx.x * 2, b = blockIdx.y;
  const int tid = threadIdx.x;
  const int l = tid & 63;
  const int w = tid >> 6;
  const int yrow = w & 1;
  const int pxq = w >> 1;
  const int lm = l & 31;
  const int lh = l >> 5;

  floatx16 acc[4];  // [mf][nblk] -> acc[mf*2+nblk]
  #pragma unroll
  for (int mf = 0; mf < 4; ++mf)
    #pragma unroll
    for (int r = 0; r < 16; ++r) acc[mf][r] = 0.f;

  const int xbase = pxq * 64 + lm;

  // staging: widx = tid + i*512, i in 0..7 -> (r 0..3, xp in 1..256, co)
  short8 stg[8];

  auto issue = [&](int q) {
    const short* __restrict__ src = ((q < 2) ? in1 : in2) + (size_t)(q & 1) * PLANE;
    #pragma unroll
    for (int i = 0; i < 8; ++i) {
      int widx = tid + i * 512;
      int r = widx >> 10;
      int xp = ((widx >> 2) & 255) + 1;
      int co = (widx & 3) << 3;
      int yy = y0 + r - 1;
      short8 v = {0, 0, 0, 0, 0, 0, 0, 0};
      if ((unsigned)yy < 256u)
        v = *(const short8*)(src + ((b * 256 + yy) * 256 + (xp - 1)) * 32 + co);
      stg[i] = v;
    }
  };
  auto commit = [&]() {
    #pragma unroll
    for (int i = 0; i < 8; ++i) {
      int widx = tid + i * 512;
      int r = widx >> 10;
      int xp = ((widx >> 2) & 255) + 1;
      int co = (widx & 3) << 3;
      *(short8*)(smem + ldsAddr(r, xp, co)) = stg[i];
    }
  };

  // zero the constant x-pad columns (xp=0, 257) once; chunk writes never
  // touch these bytes (ldsAddr is injective).
  if (tid < 32) {
    short8 z = {0, 0, 0, 0, 0, 0, 0, 0};
    int r = tid >> 3;
    int xp = (tid & 4) ? 257 : 0;
    int co = (tid & 3) << 3;
    *(short8*)(smem + ldsAddr(r, xp, co)) = z;
  }

  issue(0);
  commit();
  __syncthreads();

  #pragma unroll
  for (int q = 0; q < NCHUNK; ++q) {
    if (q + 1 < NCHUNK) issue(q + 1);   // loads fly under the MFMA phase

    #pragma unroll
    for (int ky = 0; ky < 3; ++ky)
    #pragma unroll
    for (int kx = 0; kx < 3; ++kx)
    #pragma unroll
    for (int s = 0; s < 2; ++s) {
      const int ks = (q * 9 + ky * 3 + kx) * 2 + s;
      const short8 bw0 = *(const short8*)(wp + ((ks * 2 + 0) * 64 + l) * 8);
      const short8 bw1 = *(const short8*)(wp + ((ks * 2 + 1) * 64 + l) * 8);
      const int cl = s * 16 + lh * 8;
      #pragma unroll
      for (int mf = 0; mf < 2; ++mf) {
        const int xp = xbase + mf * 32 + kx;
        const short8 av = *(const short8*)(smem + ldsAddr(yrow + ky, xp, cl));
        acc[mf * 2 + 0] = __builtin_amdgcn_mfma_f32_32x32x16_bf16(av, bw0, acc[mf * 2 + 0], 0, 0, 0);
        acc[mf * 2 + 1] = __builtin_amdgcn_mfma_f32_32x32x16_bf16(av, bw1, acc[mf * 2 + 1], 0, 0, 0);
      }
    }

    if (q + 1 < NCHUNK) {
      __syncthreads();   // all waves done reading LDS chunk q
      commit();
      __syncthreads();   // chunk q+1 visible
    }
  }

  const float alp = alpha[0];
  const int y = y0 + yrow;
  #pragma unroll
  for (int nb = 0; nb < 2; ++nb) {
    const float bs = bias[nb * 32 + lm];
    short* __restrict__ op = out + (size_t)nb * PLANE + lm;
    #pragma unroll
    for (int mf = 0; mf < 2; ++mf) {
      #pragma unroll
      for (int r = 0; r < 16; ++r) {
        int px = pxq * 64 + mf * 32 + (r & 3) + ((r >> 2) << 3) + (lh << 2);
        float v = acc[mf * 2 + nb][r] + bs;
        v = v >= 0.f ? v : alp * v;
        op[((b * 256 + y) * 256 + px) * 32] = f2b(v);
      }
    }
  }
}

// ---------------------------------------------------------------------------
// Weight pre-pack (round-4 order: ks = (q*9 + tap)*2 + s).
// element (ks, nblk, lane, e) = W[cout = nblk*32 + lane&31][cin = q*32 + s*16 + 8*(lane>>5) + e]
// ---------------------------------------------------------------------------
__global__ __launch_bounds__(256)
void k_pack(const float* __restrict__ w2, const float* __restrict__ w3,
            const float* __restrict__ w4, const float* __restrict__ wf,
            short* __restrict__ wp234, short* __restrict__ wpfus)
{
  int idx = blockIdx.x * 256 + threadIdx.x;
  if (idx < 24 * 36864) {
    int conv = idx / 36864;
    int r = idx - conv * 36864;
    int which = conv >> 3, g = conv & 7;
    const float* W = (which == 0 ? w2 : which == 1 ? w3 : w4) + g * 36864;
    int ks = r >> 10;
    int nblk = (r >> 9) & 1;
    int lane = (r >> 3) & 63;
    int e = r & 7;
    int q = ks / 18, tt = ks % 18;
    int t = tt >> 1, s = tt & 1;
    int cin = q * 32 + s * 16 + ((lane >> 5) << 3) + e;
    int cout = nblk * 32 + (lane & 31);
    int ky = t / 3, kx = t % 3;
    wp234[idx] = f2b(W[((cout * 64 + cin) * 3 + ky) * 3 + kx]);
  } else {
    int idx2 = idx - 24 * 36864;
    if (idx2 >= 7 * 73728) return;
    int conv = idx2 / 73728;
    int r = idx2 - conv * 73728;
    const float* W = wf + conv * 73728;
    int ks = r >> 10;
    int nblk = (r >> 9) & 1;
    int lane = (r >> 3) & 63;
    int e = r & 7;
    int q = ks / 18, tt = ks % 18;
    int t = tt >> 1, s = tt & 1;
    int cin = q * 32 + s * 16 + ((lane >> 5) << 3) + e;
    int cout = nblk * 32 + (lane & 31);
    int ky = t / 3, kx = t % 3;
    wpfus[idx2] = f2b(W[((cout * 128 + cin) * 3 + ky) * 3 + kx]);
  }
}

// ---------------------------------------------------------------------------
// Head stage 1: sample conv (32x32, stride 32). s_all[g][b][c][gy][gx], fp32.
// ---------------------------------------------------------------------------
__global__ __launch_bounds__(256)
void k_sample(const float* __restrict__ x, const float* __restrict__ sw,
              float* __restrict__ s_all)
{
  int idx = blockIdx.x * 256 + threadIdx.x;  // 8*8*13*64 = 53248 threads
  int gx = idx & 7, gy = (idx >> 3) & 7;
  int t = idx >> 6;
  int c = t % 13; t /= 13;
  int b = t & 7, g = t >> 3;
  const float* xb = x + b * 65536 + (gy * 32) * 256 + gx * 32;
  const float* wp = sw + (g * 13 + c) * 1024;
  float acc = 0.f;
  for (int i = 0; i < 32; ++i) {
    #pragma unroll
    for (int j = 0; j < 32; ++j) acc += xb[i * 256 + j] * wp[i * 32 + j];
  }
  s_all[idx] = acc;
}

// ---------------------------------------------------------------------------
// Head stage 2: 1x1 up conv + bias, fused with depth_to_space.
// z_all[g][b][y][x] fp32, pos = (y%32)*32 + (x%32).
// ---------------------------------------------------------------------------
__global__ __launch_bounds__(256)
void k_upz(const float* __restrict__ s_all, const float* __restrict__ upw,
           const float* __restrict__ upb, float* __restrict__ z_all)
{
  int idx = blockIdx.x * 256 + threadIdx.x;  // 4194304
  int x = idx & 255, y = (idx >> 8) & 255;
  int b = (idx >> 16) & 7, g = idx >> 19;
  int pos = (y & 31) * 32 + (x & 31);
  int gy = y >> 5, gx = x >> 5;
  const float* sp = s_all + ((g * 8 + b) * 13) * 64 + gy * 8 + gx;
  const float* wp = upw + (g * 1024 + pos) * 13;
  float a = upb[g * 1024 + pos];
  #pragma unroll
  for (int c = 0; c < 13; ++c) a += wp[c] * sp[c * 64];
  z_all[idx] = a;
}

// ---------------------------------------------------------------------------
// Head stage 3: conv1 (1 -> 64, 3x3, pad 1) + PReLU, writes split-plane bf16.
// ---------------------------------------------------------------------------
__global__ __launch_bounds__(256)
void k_conv1(const float* __restrict__ z, const float* __restrict__ w,
             const float* __restrict__ bias, const float* __restrict__ alpha,
             short* __restrict__ out)
{
  int pid = blockIdx.x * 256 + threadIdx.x;  // b*65536 + y*256 + x
  int x = pid & 255, y = (pid >> 8) & 255, b = pid >> 16;
  float zv[9];
  #pragma unroll
  for (int t = 0; t < 9; ++t) {
    int dy = t / 3, dx = t % 3;
    int yy = y + dy - 1, xx = x + dx - 1;
    zv[t] = ((unsigned)yy < 256u && (unsigned)xx < 256u)
              ? z[b * 65536 + yy * 256 + xx] : 0.f;
  }
  float alp = alpha[0];
  #pragma unroll
  for (int c0 = 0; c0 < 64; c0 += 8) {
    short8 pack;
    #pragma unroll
    for (int e = 0; e < 8; ++e) {
      int c = c0 + e;
      float a = bias[c];
      #pragma unroll
      for (int t = 0; t < 9; ++t) a += w[c * 9 + t] * zv[t];
      a = a >= 0.f ? a : alp * a;
      pack[e] = f2b(a);
    }
    *(short8*)(out + (size_t)(c0 >> 5) * PLANE + pid * 32 + (c0 & 31)) = pack;
  }
}

// ---------------------------------------------------------------------------
// t5: 64 -> 1, 3x3, pad 1, + bias, fp32 output into d_out slice.
// ---------------------------------------------------------------------------
__global__ __launch_bounds__(256)
void k_t5(const short* __restrict__ in, const float* __restrict__ w,
          const float* __restrict__ bias, float* __restrict__ out)
{
  int pid = blockIdx.x * 256 + threadIdx.x;
  int x = pid & 255, y = (pid >> 8) & 255, b = pid >> 16;
  float acc = bias[0];
  for (int dy = 0; dy < 3; ++dy) {
    int yy = y + dy - 1;
    if ((unsigned)yy >= 256u) continue;
    for (int dx = 0; dx < 3; ++dx) {
      int xx = x + dx - 1;
      if ((unsigned)xx >= 256u) continue;
      const int pix = (b * 256 + yy) * 256 + xx;
      #pragma unroll
      for (int c0 = 0; c0 < 64; c0 += 8) {
        short8 v = *(const short8*)(in + (size_t)(c0 >> 5) * PLANE + pix * 32 + (c0 & 31));
        #pragma unroll
        for (int e = 0; e < 8; ++e)
          acc += w[(c0 + e) * 9 + dy * 3 + dx] * b2f(v[e]);
      }
    }
  }
  out[pid] = acc;
}

// ---------------------------------------------------------------------------
extern "C" void kernel_launch(void* const* d_in, const int* in_sizes, int n_in,
                              void* d_out, int out_size, void* d_ws, size_t ws_size,
                              hipStream_t stream) {
  const float* X   = (const float*)d_in[0];
  const float* SW  = (const float*)d_in[1];
  const float* UPW = (const float*)d_in[2];
  const float* UPB = (const float*)d_in[3];
  const float* C1W = (const float*)d_in[4];
  const float* C1B = (const float*)d_in[5];
  const float* C1A = (const float*)d_in[6];
  const float* FW  = (const float*)d_in[7];
  const float* FB  = (const float*)d_in[8];
  const float* FA  = (const float*)d_in[9];
  const float* W2  = (const float*)d_in[10];
  const float* B2  = (const float*)d_in[11];
  const float* A2  = (const float*)d_in[12];
  const float* W3  = (const float*)d_in[13];
  const float* B3  = (const float*)d_in[14];
  const float* A3  = (const float*)d_in[15];
  const float* W4  = (const float*)d_in[16];
  const float* B4  = (const float*)d_in[17];
  const float* A4  = (const float*)d_in[18];
  const float* W5  = (const float*)d_in[19];
  const float* B5  = (const float*)d_in[20];
  float* OUT = (float*)d_out;
  (void)in_sizes; (void)n_in; (void)out_size; (void)ws_size;

  uint8_t* base = (uint8_t*)d_ws;
  size_t off = 0;
  auto alloc = [&](size_t bytes) -> uint8_t* {
    uint8_t* r = base + off;
    off += (bytes + 255) & ~(size_t)255;
    return r;
  };
  const size_t ACT_ELEMS = 2ull * PLANE;               // 33,554,432 bf16
  short* act[3];
  for (int i = 0; i < 3; ++i) act[i] = (short*)alloc(ACT_ELEMS * 2);
  float* z_all = (float*)alloc(4194304ull * 4);
  float* s_all = (float*)alloc(53248ull * 4);
  short* wp234 = (short*)alloc(884736ull * 2);
  short* wpfus = (short*)alloc(516096ull * 2);

  k_pack<<<dim3(5472), dim3(256), 0, stream>>>(W2, W3, W4, FW, wp234, wpfus);
  k_sample<<<dim3(208), dim3(256), 0, stream>>>(X, SW, s_all);
  k_upz<<<dim3(16384), dim3(256), 0, stream>>>(s_all, UPW, UPB, z_all);

  int cur = 0, A = 1, B = 2;
  // head(0) -> cur
  k_conv1<<<dim3(2048), dim3(256), 0, stream>>>(z_all, C1W, C1B, C1A, act[cur]);

  for (int m = 0; m < 8; ++m) {
    const short* wp_t2 = wp234 + (0 * 8 + m) * 36864;
    const short* wp_t3 = wp234 + (1 * 8 + m) * 36864;
    const short* wp_t4 = wp234 + (2 * 8 + m) * 36864;

    k_conv<2><<<dim3(128, 8), dim3(512), 0, stream>>>(
        act[cur], act[cur], wp_t2, B2 + m * 64, A2 + m, act[A]);
    k_conv<2><<<dim3(128, 8), dim3(512), 0, stream>>>(
        act[A], act[A], wp_t3, B3 + m * 64, A3 + m, act[B]);
    k_conv<2><<<dim3(128, 8), dim3(512), 0, stream>>>(
        act[B], act[B], wp_t4, B4 + m * 64, A4 + m, act[A]);
    k_t5<<<dim3(2048), dim3(256), 0, stream>>>(
        act[A], W5 + m * 576, B5 + m, OUT + (size_t)m * 524288);

    if (m < 7) {
      // head(m+1) -> act[B] (free after t4 consumed it)
      k_conv1<<<dim3(2048), dim3(256), 0, stream>>>(
          z_all + (size_t)(m + 1) * 524288, C1W + (m + 1) * 576,
          C1B + (m + 1) * 64, C1A + (m + 1), act[B]);
      // fus(cur, head) -> act[A] (free after t5 consumed it)
      k_conv<4><<<dim3(128, 8), dim3(512), 0, stream>>>(
          act[cur], act[B], wpfus + m * 73728, FB + m * 64, FA + m, act[A]);
      int tmp = cur; cur = A; A = tmp;  // new cur = fus output
    }
  }
}

// Round 13
// 3107.044 us; speedup vs baseline: 1.1557x; 1.1008x over previous
//
#include <hip/hip_runtime.h>
#include <stdint.h>

typedef __attribute__((ext_vector_type(8))) short short8;
typedef __attribute__((ext_vector_type(16))) float floatx16;

#define PLANE 16777216  // 8*256*256*32 elems: one 32-channel plane of an activation

__device__ __forceinline__ float b2f(short s) {
  union { uint32_t u; float f; } v; v.u = ((uint32_t)(uint16_t)s) << 16; return v.f;
}
__device__ __forceinline__ short f2b(float f) {
  union { float f; uint32_t u; } v; v.f = f;
  uint32_t r = (v.u + 0x7FFFu + ((v.u >> 16) & 1u)) >> 16;
  return (short)r;
}

// LDS tile: [4 rows][258 xp][32 c] bf16, 64 B per (r,xp) row, XOR-swizzled.
// Same formula on write & read; injective (validated rounds 1-12).
__device__ __forceinline__ uint32_t ldsAddr(int r, int xp, int c) {
  uint32_t byte = ((uint32_t)(r * 258 + xp) << 6) + ((uint32_t)c << 1);
  byte ^= ((uint32_t)(xp & 7)) << 4;
  return byte;
}

// ---------------------------------------------------------------------------
// Main MFMA conv: 3x3, pad 1, C_in = 32*NCHUNK (chunks 0,1 = planes of in1,
// chunks 2,3 = planes of in2), C_out = 64, PReLU.
// Activations: split-plane NHWC bf16 [plane][8][256][256][32].
// Block: 2 output rows, 512 threads = 8 waves: w&1 = y row, w>>1 = px quarter.
// Each wave: 2 mf (px) x 2 nblk (cout). T14 async-stage between chunks.
//
// SESSION LAWS (hardware-verified):
//  - 1024-thr blocks force 64 VGPR -> spill; min-waves capping VGPR<130 ->
//    spill; (512,2) safe. WRITE_SIZE>65.5MB = spill canary. (r3/5/6)
//  - Source-level changes to the inner loop (reorders r7, extra VALU r9,
//    manual addr hoisting r11, dbuf r10) all defeat the compiler's schedule.
//  - R12 reproduction test: identical source gave different codegen/time
//    than R4's bench (environment drift). Only post-R7 results comparable.
//  - XCD-affine decode (this kernel): t-conv FETCH 133->69 MB (halo served
//    from same-XCD L2) and best post-drift total (r8: 3116 vs plateau 3400).
//
// XCD-affine block decode: linear wgid % 8 = XCD; b = wg & 7, ytile = wg>>3,
// so XCD k owns batch k entirely and y-halo rows shared by adjacent ytiles
// are L2-local.
//
// A-frag k-map and B-frag pack share the same k-permutation (cancels).
// C/D: col(=cout_local)=lane&31, row(=px_local)=(r&3)+8*(r>>2)+4*(lane>>5)
// ---------------------------------------------------------------------------
template<int NCHUNK>
__global__ __launch_bounds__(512, 2)
void k_conv(const short* __restrict__ in1, const short* __restrict__ in2,
            const short* __restrict__ wp, const float* __restrict__ bias,
            const float* __restrict__ alpha, short* __restrict__ out)
{
  __shared__ __align__(16) uint8_t smem[4 * 258 * 64];
  const int wg = blockIdx.x;          // 0..1023
  const int b = wg & 7;               // = XCD id under linear round-robin
  const int y0 = (wg >> 3) * 2;       // consecutive ytiles share an XCD
  const int tid = threadIdx.x;
  const int l = tid & 63;
  const int w = tid >> 6;
  const int yrow = w & 1;
  const int pxq = w >> 1;
  const int lm = l & 31;
  const int lh = l >> 5;

  floatx16 acc[4];  // [mf][nblk] -> acc[mf*2+nblk]
  #pragma unroll
  for (int mf = 0; mf < 4; ++mf)
    #pragma unroll
    for (int r = 0; r < 16; ++r) acc[mf][r] = 0.f;

  const int xbase = pxq * 64 + lm;

  // staging: widx = tid + i*512, i in 0..7 -> (r 0..3, xp in 1..256, co)
  short8 stg[8];

  auto issue = [&](int q) {
    const short* __restrict__ src = ((q < 2) ? in1 : in2) + (size_t)(q & 1) * PLANE;
    #pragma unroll
    for (int i = 0; i < 8; ++i) {
      int widx = tid + i * 512;
      int r = widx >> 10;
      int xp = ((widx >> 2) & 255) + 1;
      int co = (widx & 3) << 3;
      int yy = y0 + r - 1;
      short8 v = {0, 0, 0, 0, 0, 0, 0, 0};
      if ((unsigned)yy < 256u)
        v = *(const short8*)(src + ((b * 256 + yy) * 256 + (xp - 1)) * 32 + co);
      stg[i] = v;
    }
  };
  auto commit = [&]() {
    #pragma unroll
    for (int i = 0; i < 8; ++i) {
      int widx = tid + i * 512;
      int r = widx >> 10;
      int xp = ((widx >> 2) & 255) + 1;
      int co = (widx & 3) << 3;
      *(short8*)(smem + ldsAddr(r, xp, co)) = stg[i];
    }
  };

  // zero the constant x-pad columns (xp=0, 257) once; chunk writes never
  // touch these bytes (ldsAddr is injective).
  if (tid < 32) {
    short8 z = {0, 0, 0, 0, 0, 0, 0, 0};
    int r = tid >> 3;
    int xp = (tid & 4) ? 257 : 0;
    int co = (tid & 3) << 3;
    *(short8*)(smem + ldsAddr(r, xp, co)) = z;
  }

  issue(0);
  commit();
  __syncthreads();

  #pragma unroll
  for (int q = 0; q < NCHUNK; ++q) {
    if (q + 1 < NCHUNK) issue(q + 1);   // loads fly under the MFMA phase

    #pragma unroll
    for (int ky = 0; ky < 3; ++ky)
    #pragma unroll
    for (int kx = 0; kx < 3; ++kx)
    #pragma unroll
    for (int s = 0; s < 2; ++s) {
      const int ks = (q * 9 + ky * 3 + kx) * 2 + s;
      const short8 bw0 = *(const short8*)(wp + ((ks * 2 + 0) * 64 + l) * 8);
      const short8 bw1 = *(const short8*)(wp + ((ks * 2 + 1) * 64 + l) * 8);
      const int cl = s * 16 + lh * 8;
      #pragma unroll
      for (int mf = 0; mf < 2; ++mf) {
        const int xp = xbase + mf * 32 + kx;
        const short8 av = *(const short8*)(smem + ldsAddr(yrow + ky, xp, cl));
        acc[mf * 2 + 0] = __builtin_amdgcn_mfma_f32_32x32x16_bf16(av, bw0, acc[mf * 2 + 0], 0, 0, 0);
        acc[mf * 2 + 1] = __builtin_amdgcn_mfma_f32_32x32x16_bf16(av, bw1, acc[mf * 2 + 1], 0, 0, 0);
      }
    }

    if (q + 1 < NCHUNK) {
      __syncthreads();   // all waves done reading LDS chunk q
      commit();
      __syncthreads();   // chunk q+1 visible
    }
  }

  const float alp = alpha[0];
  const int y = y0 + yrow;
  #pragma unroll
  for (int nb = 0; nb < 2; ++nb) {
    const float bs = bias[nb * 32 + lm];
    short* __restrict__ op = out + (size_t)nb * PLANE + lm;
    #pragma unroll
    for (int mf = 0; mf < 2; ++mf) {
      #pragma unroll
      for (int r = 0; r < 16; ++r) {
        int px = pxq * 64 + mf * 32 + (r & 3) + ((r >> 2) << 3) + (lh << 2);
        float v = acc[mf * 2 + nb][r] + bs;
        v = v >= 0.f ? v : alp * v;
        op[((b * 256 + y) * 256 + px) * 32] = f2b(v);
      }
    }
  }
}

// ---------------------------------------------------------------------------
// Weight pre-pack (ks = (q*9 + tap)*2 + s).
// element (ks, nblk, lane, e) = W[cout = nblk*32 + lane&31][cin = q*32 + s*16 + 8*(lane>>5) + e]
// ---------------------------------------------------------------------------
__global__ __launch_bounds__(256)
void k_pack(const float* __restrict__ w2, const float* __restrict__ w3,
            const float* __restrict__ w4, const float* __restrict__ wf,
            short* __restrict__ wp234, short* __restrict__ wpfus)
{
  int idx = blockIdx.x * 256 + threadIdx.x;
  if (idx < 24 * 36864) {
    int conv = idx / 36864;
    int r = idx - conv * 36864;
    int which = conv >> 3, g = conv & 7;
    const float* W = (which == 0 ? w2 : which == 1 ? w3 : w4) + g * 36864;
    int ks = r >> 10;
    int nblk = (r >> 9) & 1;
    int lane = (r >> 3) & 63;
    int e = r & 7;
    int q = ks / 18, tt = ks % 18;
    int t = tt >> 1, s = tt & 1;
    int cin = q * 32 + s * 16 + ((lane >> 5) << 3) + e;
    int cout = nblk * 32 + (lane & 31);
    int ky = t / 3, kx = t % 3;
    wp234[idx] = f2b(W[((cout * 64 + cin) * 3 + ky) * 3 + kx]);
  } else {
    int idx2 = idx - 24 * 36864;
    if (idx2 >= 7 * 73728) return;
    int conv = idx2 / 73728;
    int r = idx2 - conv * 73728;
    const float* W = wf + conv * 73728;
    int ks = r >> 10;
    int nblk = (r >> 9) & 1;
    int lane = (r >> 3) & 63;
    int e = r & 7;
    int q = ks / 18, tt = ks % 18;
    int t = tt >> 1, s = tt & 1;
    int cin = q * 32 + s * 16 + ((lane >> 5) << 3) + e;
    int cout = nblk * 32 + (lane & 31);
    int ky = t / 3, kx = t % 3;
    wpfus[idx2] = f2b(W[((cout * 128 + cin) * 3 + ky) * 3 + kx]);
  }
}

// ---------------------------------------------------------------------------
// Head stage 1: sample conv (32x32, stride 32). s_all[g][b][c][gy][gx], fp32.
// ---------------------------------------------------------------------------
__global__ __launch_bounds__(256)
void k_sample(const float* __restrict__ x, const float* __restrict__ sw,
              float* __restrict__ s_all)
{
  int idx = blockIdx.x * 256 + threadIdx.x;  // 8*8*13*64 = 53248 threads
  int gx = idx & 7, gy = (idx >> 3) & 7;
  int t = idx >> 6;
  int c = t % 13; t /= 13;
  int b = t & 7, g = t >> 3;
  const float* xb = x + b * 65536 + (gy * 32) * 256 + gx * 32;
  const float* wp = sw + (g * 13 + c) * 1024;
  float acc = 0.f;
  for (int i = 0; i < 32; ++i) {
    #pragma unroll
    for (int j = 0; j < 32; ++j) acc += xb[i * 256 + j] * wp[i * 32 + j];
  }
  s_all[idx] = acc;
}

// ---------------------------------------------------------------------------
// Head stage 2: 1x1 up conv + bias, fused with depth_to_space.
// z_all[g][b][y][x] fp32, pos = (y%32)*32 + (x%32).
// ---------------------------------------------------------------------------
__global__ __launch_bounds__(256)
void k_upz(const float* __restrict__ s_all, const float* __restrict__ upw,
           const float* __restrict__ upb, float* __restrict__ z_all)
{
  int idx = blockIdx.x * 256 + threadIdx.x;  // 4194304
  int x = idx & 255, y = (idx >> 8) & 255;
  int b = (idx >> 16) & 7, g = idx >> 19;
  int pos = (y & 31) * 32 + (x & 31);
  int gy = y >> 5, gx = x >> 5;
  const float* sp = s_all + ((g * 8 + b) * 13) * 64 + gy * 8 + gx;
  const float* wp = upw + (g * 1024 + pos) * 13;
  float a = upb[g * 1024 + pos];
  #pragma unroll
  for (int c = 0; c < 13; ++c) a += wp[c] * sp[c * 64];
  z_all[idx] = a;
}

// ---------------------------------------------------------------------------
// Head stage 3: conv1 (1 -> 64, 3x3, pad 1) + PReLU, writes split-plane bf16.
// XCD-affine: b = wgid & 7 so its writes land on the XCD that fus will read.
// ---------------------------------------------------------------------------
__global__ __launch_bounds__(256)
void k_conv1(const float* __restrict__ z, const float* __restrict__ w,
             const float* __restrict__ bias, const float* __restrict__ alpha,
             short* __restrict__ out)
{
  int wg = blockIdx.x;                 // 0..2047
  int b = wg & 7;
  int y = wg >> 3;                     // 0..255
  int x = threadIdx.x;                 // 0..255
  int pid = (b * 256 + y) * 256 + x;
  float zv[9];
  #pragma unroll
  for (int t = 0; t < 9; ++t) {
    int dy = t / 3, dx = t % 3;
    int yy = y + dy - 1, xx = x + dx - 1;
    zv[t] = ((unsigned)yy < 256u && (unsigned)xx < 256u)
              ? z[b * 65536 + yy * 256 + xx] : 0.f;
  }
  float alp = alpha[0];
  #pragma unroll
  for (int c0 = 0; c0 < 64; c0 += 8) {
    short8 pack;
    #pragma unroll
    for (int e = 0; e < 8; ++e) {
      int c = c0 + e;
      float a = bias[c];
      #pragma unroll
      for (int t = 0; t < 9; ++t) a += w[c * 9 + t] * zv[t];
      a = a >= 0.f ? a : alp * a;
      pack[e] = f2b(a);
    }
    *(short8*)(out + (size_t)(c0 >> 5) * PLANE + pid * 32 + (c0 & 31)) = pack;
  }
}

// ---------------------------------------------------------------------------
// t5: 64 -> 1, 3x3, pad 1, + bias, fp32 output into d_out slice.
// XCD-affine b = wgid & 7: reads act produced on the same XCD.
// ---------------------------------------------------------------------------
__global__ __launch_bounds__(256)
void k_t5(const short* __restrict__ in, const float* __restrict__ w,
          const float* __restrict__ bias, float* __restrict__ out)
{
  int wg = blockIdx.x;                 // 0..2047
  int b = wg & 7;
  int y = wg >> 3;                     // 0..255
  int x = threadIdx.x;                 // 0..255
  float acc = bias[0];
  for (int dy = 0; dy < 3; ++dy) {
    int yy = y + dy - 1;
    if ((unsigned)yy >= 256u) continue;
    for (int dx = 0; dx < 3; ++dx) {
      int xx = x + dx - 1;
      if ((unsigned)xx >= 256u) continue;
      const int pix = (b * 256 + yy) * 256 + xx;
      #pragma unroll
      for (int c0 = 0; c0 < 64; c0 += 8) {
        short8 v = *(const short8*)(in + (size_t)(c0 >> 5) * PLANE + pix * 32 + (c0 & 31));
        #pragma unroll
        for (int e = 0; e < 8; ++e)
          acc += w[(c0 + e) * 9 + dy * 3 + dx] * b2f(v[e]);
      }
    }
  }
  out[(b * 256 + y) * 256 + x] = acc;
}

// ---------------------------------------------------------------------------
extern "C" void kernel_launch(void* const* d_in, const int* in_sizes, int n_in,
                              void* d_out, int out_size, void* d_ws, size_t ws_size,
                              hipStream_t stream) {
  const float* X   = (const float*)d_in[0];
  const float* SW  = (const float*)d_in[1];
  const float* UPW = (const float*)d_in[2];
  const float* UPB = (const float*)d_in[3];
  const float* C1W = (const float*)d_in[4];
  const float* C1B = (const float*)d_in[5];
  const float* C1A = (const float*)d_in[6];
  const float* FW  = (const float*)d_in[7];
  const float* FB  = (const float*)d_in[8];
  const float* FA  = (const float*)d_in[9];
  const float* W2  = (const float*)d_in[10];
  const float* B2  = (const float*)d_in[11];
  const float* A2  = (const float*)d_in[12];
  const float* W3  = (const float*)d_in[13];
  const float* B3  = (const float*)d_in[14];
  const float* A3  = (const float*)d_in[15];
  const float* W4  = (const float*)d_in[16];
  const float* B4  = (const float*)d_in[17];
  const float* A4  = (const float*)d_in[18];
  const float* W5  = (const float*)d_in[19];
  const float* B5  = (const float*)d_in[20];
  float* OUT = (float*)d_out;
  (void)in_sizes; (void)n_in; (void)out_size; (void)ws_size;

  uint8_t* base = (uint8_t*)d_ws;
  size_t off = 0;
  auto alloc = [&](size_t bytes) -> uint8_t* {
    uint8_t* r = base + off;
    off += (bytes + 255) & ~(size_t)255;
    return r;
  };
  const size_t ACT_ELEMS = 2ull * PLANE;               // 33,554,432 bf16
  short* act[3];
  for (int i = 0; i < 3; ++i) act[i] = (short*)alloc(ACT_ELEMS * 2);
  float* z_all = (float*)alloc(4194304ull * 4);
  float* s_all = (float*)alloc(53248ull * 4);
  short* wp234 = (short*)alloc(884736ull * 2);
  short* wpfus = (short*)alloc(516096ull * 2);

  k_pack<<<dim3(5472), dim3(256), 0, stream>>>(W2, W3, W4, FW, wp234, wpfus);
  k_sample<<<dim3(208), dim3(256), 0, stream>>>(X, SW, s_all);
  k_upz<<<dim3(16384), dim3(256), 0, stream>>>(s_all, UPW, UPB, z_all);

  int cur = 0, A = 1, B = 2;
  // head(0) -> cur
  k_conv1<<<dim3(2048), dim3(256), 0, stream>>>(z_all, C1W, C1B, C1A, act[cur]);

  for (int m = 0; m < 8; ++m) {
    const short* wp_t2 = wp234 + (0 * 8 + m) * 36864;
    const short* wp_t3 = wp234 + (1 * 8 + m) * 36864;
    const short* wp_t4 = wp234 + (2 * 8 + m) * 36864;

    k_conv<2><<<dim3(1024), dim3(512), 0, stream>>>(
        act[cur], act[cur], wp_t2, B2 + m * 64, A2 + m, act[A]);
    k_conv<2><<<dim3(1024), dim3(512), 0, stream>>>(
        act[A], act[A], wp_t3, B3 + m * 64, A3 + m, act[B]);
    k_conv<2><<<dim3(1024), dim3(512), 0, stream>>>(
        act[B], act[B], wp_t4, B4 + m * 64, A4 + m, act[A]);
    k_t5<<<dim3(2048), dim3(256), 0, stream>>>(
        act[A], W5 + m * 576, B5 + m, OUT + (size_t)m * 524288);

    if (m < 7) {
      // head(m+1) -> act[B] (free after t4 consumed it)
      k_conv1<<<dim3(2048), dim3(256), 0, stream>>>(
          z_all + (size_t)(m + 1) * 524288, C1W + (m + 1) * 576,
          C1B + (m + 1) * 64, C1A + (m + 1), act[B]);
      // fus(cur, head) -> act[A] (free after t5 consumed it)
      k_conv<4><<<dim3(1024), dim3(512), 0, stream>>>(
          act[cur], act[B], wpfus + m * 73728, FB + m * 64, FA + m, act[A]);
      int tmp = cur; cur = A; A = tmp;  // new cur = fus output
    }
  }
}

// Round 14
// 3097.913 us; speedup vs baseline: 1.1591x; 1.0029x over previous
//
#include <hip/hip_runtime.h>
#include <stdint.h>

typedef __attribute__((ext_vector_type(8))) short short8;
typedef __attribute__((ext_vector_type(16))) float floatx16;

#define PLANE 16777216  // 8*256*256*32 elems: one 32-channel plane of an activation

__device__ __forceinline__ float b2f(short s) {
  union { uint32_t u; float f; } v; v.u = ((uint32_t)(uint16_t)s) << 16; return v.f;
}
__device__ __forceinline__ short f2b(float f) {
  union { float f; uint32_t u; } v; v.f = f;
  uint32_t r = (v.u + 0x7FFFu + ((v.u >> 16) & 1u)) >> 16;
  return (short)r;
}

// LDS tile: [4 rows][258 xp][32 c] bf16, 64 B per (r,xp) row, XOR-swizzled.
// Same formula on write & read; injective (validated rounds 1-13).
__device__ __forceinline__ uint32_t ldsAddr(int r, int xp, int c) {
  uint32_t byte = ((uint32_t)(r * 258 + xp) << 6) + ((uint32_t)c << 1);
  byte ^= ((uint32_t)(xp & 7)) << 4;
  return byte;
}

// ---------------------------------------------------------------------------
// Main MFMA conv: 3x3, pad 1, C_in = 32*NCHUNK (chunks 0,1 = planes of in1,
// chunks 2,3 = planes of in2), C_out = 64, PReLU.
// Activations: split-plane NHWC bf16 [plane][8][256][256][32].
// Block: 2 output rows, 512 threads = 8 waves: w&1 = y row, w>>1 = px quarter.
// Each wave: 2 mf (px) x 2 nblk (cout). T14 async-stage between chunks.
//
// SESSION LAWS (hardware-verified):
//  - 1024-thr blocks force 64 VGPR -> spill; min-waves capping VGPR<130 ->
//    spill; (512,2) safe. WRITE_SIZE>65.5MB = spill canary. (r3/5/6)
//  - Source-level changes to inner-loop addressing defeat the compiler's
//    schedule (r7/r9/r10/r11) -- do not touch loop order or address exprs.
//  - XCD-affine decode: t-conv FETCH 133->69 MB; ~9% total win, reproduced
//    twice (r8: 3116, r13: 3107 vs 3420 plateau).
//  - R14: s_setprio(1) around MFMA cluster (T5). Mechanism: 2 independent
//    blocks/CU at different phases; MFMA waves preempt staging waves.
//
// XCD-affine block decode: linear wgid % 8 = XCD; b = wg & 7, ytile = wg>>3,
// so XCD k owns batch k entirely and y-halo rows shared by adjacent ytiles
// are L2-local.
//
// A-frag k-map and B-frag pack share the same k-permutation (cancels).
// C/D: col(=cout_local)=lane&31, row(=px_local)=(r&3)+8*(r>>2)+4*(lane>>5)
// ---------------------------------------------------------------------------
template<int NCHUNK>
__global__ __launch_bounds__(512, 2)
void k_conv(const short* __restrict__ in1, const short* __restrict__ in2,
            const short* __restrict__ wp, const float* __restrict__ bias,
            const float* __restrict__ alpha, short* __restrict__ out)
{
  __shared__ __align__(16) uint8_t smem[4 * 258 * 64];
  const int wg = blockIdx.x;          // 0..1023
  const int b = wg & 7;               // = XCD id under linear round-robin
  const int y0 = (wg >> 3) * 2;       // consecutive ytiles share an XCD
  const int tid = threadIdx.x;
  const int l = tid & 63;
  const int w = tid >> 6;
  const int yrow = w & 1;
  const int pxq = w >> 1;
  const int lm = l & 31;
  const int lh = l >> 5;

  floatx16 acc[4];  // [mf][nblk] -> acc[mf*2+nblk]
  #pragma unroll
  for (int mf = 0; mf < 4; ++mf)
    #pragma unroll
    for (int r = 0; r < 16; ++r) acc[mf][r] = 0.f;

  const int xbase = pxq * 64 + lm;

  // staging: widx = tid + i*512, i in 0..7 -> (r 0..3, xp in 1..256, co)
  short8 stg[8];

  auto issue = [&](int q) {
    const short* __restrict__ src = ((q < 2) ? in1 : in2) + (size_t)(q & 1) * PLANE;
    #pragma unroll
    for (int i = 0; i < 8; ++i) {
      int widx = tid + i * 512;
      int r = widx >> 10;
      int xp = ((widx >> 2) & 255) + 1;
      int co = (widx & 3) << 3;
      int yy = y0 + r - 1;
      short8 v = {0, 0, 0, 0, 0, 0, 0, 0};
      if ((unsigned)yy < 256u)
        v = *(const short8*)(src + ((b * 256 + yy) * 256 + (xp - 1)) * 32 + co);
      stg[i] = v;
    }
  };
  auto commit = [&]() {
    #pragma unroll
    for (int i = 0; i < 8; ++i) {
      int widx = tid + i * 512;
      int r = widx >> 10;
      int xp = ((widx >> 2) & 255) + 1;
      int co = (widx & 3) << 3;
      *(short8*)(smem + ldsAddr(r, xp, co)) = stg[i];
    }
  };

  // zero the constant x-pad columns (xp=0, 257) once; chunk writes never
  // touch these bytes (ldsAddr is injective).
  if (tid < 32) {
    short8 z = {0, 0, 0, 0, 0, 0, 0, 0};
    int r = tid >> 3;
    int xp = (tid & 4) ? 257 : 0;
    int co = (tid & 3) << 3;
    *(short8*)(smem + ldsAddr(r, xp, co)) = z;
  }

  issue(0);
  commit();
  __syncthreads();

  #pragma unroll
  for (int q = 0; q < NCHUNK; ++q) {
    if (q + 1 < NCHUNK) issue(q + 1);   // loads fly under the MFMA phase

    __builtin_amdgcn_s_setprio(1);      // T5: favor MFMA waves over the
                                        // other resident block's staging
    #pragma unroll
    for (int ky = 0; ky < 3; ++ky)
    #pragma unroll
    for (int kx = 0; kx < 3; ++kx)
    #pragma unroll
    for (int s = 0; s < 2; ++s) {
      const int ks = (q * 9 + ky * 3 + kx) * 2 + s;
      const short8 bw0 = *(const short8*)(wp + ((ks * 2 + 0) * 64 + l) * 8);
      const short8 bw1 = *(const short8*)(wp + ((ks * 2 + 1) * 64 + l) * 8);
      const int cl = s * 16 + lh * 8;
      #pragma unroll
      for (int mf = 0; mf < 2; ++mf) {
        const int xp = xbase + mf * 32 + kx;
        const short8 av = *(const short8*)(smem + ldsAddr(yrow + ky, xp, cl));
        acc[mf * 2 + 0] = __builtin_amdgcn_mfma_f32_32x32x16_bf16(av, bw0, acc[mf * 2 + 0], 0, 0, 0);
        acc[mf * 2 + 1] = __builtin_amdgcn_mfma_f32_32x32x16_bf16(av, bw1, acc[mf * 2 + 1], 0, 0, 0);
      }
    }
    __builtin_amdgcn_s_setprio(0);

    if (q + 1 < NCHUNK) {
      __syncthreads();   // all waves done reading LDS chunk q
      commit();
      __syncthreads();   // chunk q+1 visible
    }
  }

  const float alp = alpha[0];
  const int y = y0 + yrow;
  #pragma unroll
  for (int nb = 0; nb < 2; ++nb) {
    const float bs = bias[nb * 32 + lm];
    short* __restrict__ op = out + (size_t)nb * PLANE + lm;
    #pragma unroll
    for (int mf = 0; mf < 2; ++mf) {
      #pragma unroll
      for (int r = 0; r < 16; ++r) {
        int px = pxq * 64 + mf * 32 + (r & 3) + ((r >> 2) << 3) + (lh << 2);
        float v = acc[mf * 2 + nb][r] + bs;
        v = v >= 0.f ? v : alp * v;
        op[((b * 256 + y) * 256 + px) * 32] = f2b(v);
      }
    }
  }
}

// ---------------------------------------------------------------------------
// Weight pre-pack (ks = (q*9 + tap)*2 + s).
// element (ks, nblk, lane, e) = W[cout = nblk*32 + lane&31][cin = q*32 + s*16 + 8*(lane>>5) + e]
// ---------------------------------------------------------------------------
__global__ __launch_bounds__(256)
void k_pack(const float* __restrict__ w2, const float* __restrict__ w3,
            const float* __restrict__ w4, const float* __restrict__ wf,
            short* __restrict__ wp234, short* __restrict__ wpfus)
{
  int idx = blockIdx.x * 256 + threadIdx.x;
  if (idx < 24 * 36864) {
    int conv = idx / 36864;
    int r = idx - conv * 36864;
    int which = conv >> 3, g = conv & 7;
    const float* W = (which == 0 ? w2 : which == 1 ? w3 : w4) + g * 36864;
    int ks = r >> 10;
    int nblk = (r >> 9) & 1;
    int lane = (r >> 3) & 63;
    int e = r & 7;
    int q = ks / 18, tt = ks % 18;
    int t = tt >> 1, s = tt & 1;
    int cin = q * 32 + s * 16 + ((lane >> 5) << 3) + e;
    int cout = nblk * 32 + (lane & 31);
    int ky = t / 3, kx = t % 3;
    wp234[idx] = f2b(W[((cout * 64 + cin) * 3 + ky) * 3 + kx]);
  } else {
    int idx2 = idx - 24 * 36864;
    if (idx2 >= 7 * 73728) return;
    int conv = idx2 / 73728;
    int r = idx2 - conv * 73728;
    const float* W = wf + conv * 73728;
    int ks = r >> 10;
    int nblk = (r >> 9) & 1;
    int lane = (r >> 3) & 63;
    int e = r & 7;
    int q = ks / 18, tt = ks % 18;
    int t = tt >> 1, s = tt & 1;
    int cin = q * 32 + s * 16 + ((lane >> 5) << 3) + e;
    int cout = nblk * 32 + (lane & 31);
    int ky = t / 3, kx = t % 3;
    wpfus[idx2] = f2b(W[((cout * 128 + cin) * 3 + ky) * 3 + kx]);
  }
}

// ---------------------------------------------------------------------------
// Head stage 1: sample conv (32x32, stride 32). s_all[g][b][c][gy][gx], fp32.
// ---------------------------------------------------------------------------
__global__ __launch_bounds__(256)
void k_sample(const float* __restrict__ x, const float* __restrict__ sw,
              float* __restrict__ s_all)
{
  int idx = blockIdx.x * 256 + threadIdx.x;  // 8*8*13*64 = 53248 threads
  int gx = idx & 7, gy = (idx >> 3) & 7;
  int t = idx >> 6;
  int c = t % 13; t /= 13;
  int b = t & 7, g = t >> 3;
  const float* xb = x + b * 65536 + (gy * 32) * 256 + gx * 32;
  const float* wp = sw + (g * 13 + c) * 1024;
  float acc = 0.f;
  for (int i = 0; i < 32; ++i) {
    #pragma unroll
    for (int j = 0; j < 32; ++j) acc += xb[i * 256 + j] * wp[i * 32 + j];
  }
  s_all[idx] = acc;
}

// ---------------------------------------------------------------------------
// Head stage 2: 1x1 up conv + bias, fused with depth_to_space.
// z_all[g][b][y][x] fp32, pos = (y%32)*32 + (x%32).
// ---------------------------------------------------------------------------
__global__ __launch_bounds__(256)
void k_upz(const float* __restrict__ s_all, const float* __restrict__ upw,
           const float* __restrict__ upb, float* __restrict__ z_all)
{
  int idx = blockIdx.x * 256 + threadIdx.x;  // 4194304
  int x = idx & 255, y = (idx >> 8) & 255;
  int b = (idx >> 16) & 7, g = idx >> 19;
  int pos = (y & 31) * 32 + (x & 31);
  int gy = y >> 5, gx = x >> 5;
  const float* sp = s_all + ((g * 8 + b) * 13) * 64 + gy * 8 + gx;
  const float* wp = upw + (g * 1024 + pos) * 13;
  float a = upb[g * 1024 + pos];
  #pragma unroll
  for (int c = 0; c < 13; ++c) a += wp[c] * sp[c * 64];
  z_all[idx] = a;
}

// ---------------------------------------------------------------------------
// Head stage 3: conv1 (1 -> 64, 3x3, pad 1) + PReLU, writes split-plane bf16.
// XCD-affine: b = wgid & 7 so its writes land on the XCD that fus will read.
// ---------------------------------------------------------------------------
__global__ __launch_bounds__(256)
void k_conv1(const float* __restrict__ z, const float* __restrict__ w,
             const float* __restrict__ bias, const float* __restrict__ alpha,
             short* __restrict__ out)
{
  int wg = blockIdx.x;                 // 0..2047
  int b = wg & 7;
  int y = wg >> 3;                     // 0..255
  int x = threadIdx.x;                 // 0..255
  int pid = (b * 256 + y) * 256 + x;
  float zv[9];
  #pragma unroll
  for (int t = 0; t < 9; ++t) {
    int dy = t / 3, dx = t % 3;
    int yy = y + dy - 1, xx = x + dx - 1;
    zv[t] = ((unsigned)yy < 256u && (unsigned)xx < 256u)
              ? z[b * 65536 + yy * 256 + xx] : 0.f;
  }
  float alp = alpha[0];
  #pragma unroll
  for (int c0 = 0; c0 < 64; c0 += 8) {
    short8 pack;
    #pragma unroll
    for (int e = 0; e < 8; ++e) {
      int c = c0 + e;
      float a = bias[c];
      #pragma unroll
      for (int t = 0; t < 9; ++t) a += w[c * 9 + t] * zv[t];
      a = a >= 0.f ? a : alp * a;
      pack[e] = f2b(a);
    }
    *(short8*)(out + (size_t)(c0 >> 5) * PLANE + pid * 32 + (c0 & 31)) = pack;
  }
}

// ---------------------------------------------------------------------------
// t5: 64 -> 1, 3x3, pad 1, + bias, fp32 output into d_out slice.
// XCD-affine b = wgid & 7: reads act produced on the same XCD.
// ---------------------------------------------------------------------------
__global__ __launch_bounds__(256)
void k_t5(const short* __restrict__ in, const float* __restrict__ w,
          const float* __restrict__ bias, float* __restrict__ out)
{
  int wg = blockIdx.x;                 // 0..2047
  int b = wg & 7;
  int y = wg >> 3;                     // 0..255
  int x = threadIdx.x;                 // 0..255
  float acc = bias[0];
  for (int dy = 0; dy < 3; ++dy) {
    int yy = y + dy - 1;
    if ((unsigned)yy >= 256u) continue;
    for (int dx = 0; dx < 3; ++dx) {
      int xx = x + dx - 1;
      if ((unsigned)xx >= 256u) continue;
      const int pix = (b * 256 + yy) * 256 + xx;
      #pragma unroll
      for (int c0 = 0; c0 < 64; c0 += 8) {
        short8 v = *(const short8*)(in + (size_t)(c0 >> 5) * PLANE + pix * 32 + (c0 & 31));
        #pragma unroll
        for (int e = 0; e < 8; ++e)
          acc += w[(c0 + e) * 9 + dy * 3 + dx] * b2f(v[e]);
      }
    }
  }
  out[(b * 256 + y) * 256 + x] = acc;
}

// ---------------------------------------------------------------------------
extern "C" void kernel_launch(void* const* d_in, const int* in_sizes, int n_in,
                              void* d_out, int out_size, void* d_ws, size_t ws_size,
                              hipStream_t stream) {
  const float* X   = (const float*)d_in[0];
  const float* SW  = (const float*)d_in[1];
  const float* UPW = (const float*)d_in[2];
  const float* UPB = (const float*)d_in[3];
  const float* C1W = (const float*)d_in[4];
  const float* C1B = (const float*)d_in[5];
  const float* C1A = (const float*)d_in[6];
  const float* FW  = (const float*)d_in[7];
  const float* FB  = (const float*)d_in[8];
  const float* FA  = (const float*)d_in[9];
  const float* W2  = (const float*)d_in[10];
  const float* B2  = (const float*)d_in[11];
  const float* A2  = (const float*)d_in[12];
  const float* W3  = (const float*)d_in[13];
  const float* B3  = (const float*)d_in[14];
  const float* A3  = (const float*)d_in[15];
  const float* W4  = (const float*)d_in[16];
  const float* B4  = (const float*)d_in[17];
  const float* A4  = (const float*)d_in[18];
  const float* W5  = (const float*)d_in[19];
  const float* B5  = (const float*)d_in[20];
  float* OUT = (float*)d_out;
  (void)in_sizes; (void)n_in; (void)out_size; (void)ws_size;

  uint8_t* base = (uint8_t*)d_ws;
  size_t off = 0;
  auto alloc = [&](size_t bytes) -> uint8_t* {
    uint8_t* r = base + off;
    off += (bytes + 255) & ~(size_t)255;
    return r;
  };
  const size_t ACT_ELEMS = 2ull * PLANE;               // 33,554,432 bf16
  short* act[3];
  for (int i = 0; i < 3; ++i) act[i] = (short*)alloc(ACT_ELEMS * 2);
  float* z_all = (float*)alloc(4194304ull * 4);
  float* s_all = (float*)alloc(53248ull * 4);
  short* wp234 = (short*)alloc(884736ull * 2);
  short* wpfus = (short*)alloc(516096ull * 2);

  k_pack<<<dim3(5472), dim3(256), 0, stream>>>(W2, W3, W4, FW, wp234, wpfus);
  k_sample<<<dim3(208), dim3(256), 0, stream>>>(X, SW, s_all);
  k_upz<<<dim3(16384), dim3(256), 0, stream>>>(s_all, UPW, UPB, z_all);

  int cur = 0, A = 1, B = 2;
  // head(0) -> cur
  k_conv1<<<dim3(2048), dim3(256), 0, stream>>>(z_all, C1W, C1B, C1A, act[cur]);

  for (int m = 0; m < 8; ++m) {
    const short* wp_t2 = wp234 + (0 * 8 + m) * 36864;
    const short* wp_t3 = wp234 + (1 * 8 + m) * 36864;
    const short* wp_t4 = wp234 + (2 * 8 + m) * 36864;

    k_conv<2><<<dim3(1024), dim3(512), 0, stream>>>(
        act[cur], act[cur], wp_t2, B2 + m * 64, A2 + m, act[A]);
    k_conv<2><<<dim3(1024), dim3(512), 0, stream>>>(
        act[A], act[A], wp_t3, B3 + m * 64, A3 + m, act[B]);
    k_conv<2><<<dim3(1024), dim3(512), 0, stream>>>(
        act[B], act[B], wp_t4, B4 + m * 64, A4 + m, act[A]);
    k_t5<<<dim3(2048), dim3(256), 0, stream>>>(
        act[A], W5 + m * 576, B5 + m, OUT + (size_t)m * 524288);

    if (m < 7) {
      // head(m+1) -> act[B] (free after t4 consumed it)
      k_conv1<<<dim3(2048), dim3(256), 0, stream>>>(
          z_all + (size_t)(m + 1) * 524288, C1W + (m + 1) * 576,
          C1B + (m + 1) * 64, C1A + (m + 1), act[B]);
      // fus(cur, head) -> act[A] (free after t5 consumed it)
      k_conv<4><<<dim3(1024), dim3(512), 0, stream>>>(
          act[cur], act[B], wpfus + m * 73728, FB + m * 64, FA + m, act[A]);
      int tmp = cur; cur = A; A = tmp;  // new cur = fus output
    }
  }
}

// Round 15
// 2908.274 us; speedup vs baseline: 1.2346x; 1.0652x over previous
//
#include <hip/hip_runtime.h>
#include <stdint.h>

typedef __attribute__((ext_vector_type(8))) short short8;
typedef __attribute__((ext_vector_type(16))) float floatx16;

#define PLANE 16777216  // 8*256*256*32 elems: one 32-channel plane of an activation

__device__ __forceinline__ float b2f(short s) {
  union { uint32_t u; float f; } v; v.u = ((uint32_t)(uint16_t)s) << 16; return v.f;
}
__device__ __forceinline__ short f2b(float f) {
  union { float f; uint32_t u; } v; v.f = f;
  uint32_t r = (v.u + 0x7FFFu + ((v.u >> 16) & 1u)) >> 16;
  return (short)r;
}

// LDS tile: [3 rows][258 xp][32 c] bf16, 64 B per (r,xp) row, XOR-swizzled.
// Same formula on write & read; injective (validated rounds 1-14).
__device__ __forceinline__ uint32_t ldsAddr(int r, int xp, int c) {
  uint32_t byte = ((uint32_t)(r * 258 + xp) << 6) + ((uint32_t)c << 1);
  byte ^= ((uint32_t)(xp & 7)) << 4;
  return byte;
}

// ---------------------------------------------------------------------------
// Main MFMA conv: 3x3, pad 1, C_in = 32*NCHUNK (chunks 0,1 = planes of in1,
// chunks 2,3 = planes of in2), C_out = 64, PReLU.
// Activations: split-plane NHWC bf16 [plane][8][256][256][32].
//
// ROUND-15: 1-row block, 3-row halo tile -> LDS 49.5 KB -> 3 blocks/CU
// (24 waves, was 16). 512 threads = 8 waves; wave w owns px [w*32,w*32+32)
// x both cout blocks (acc 32 VGPR, stg 6 -> body ~80 VGPR; go/no-go: must
// be <=84 for 3 blocks/CU). Halo redundancy 1.5->3x is served by same-XCD
// L2 (HBM at 15%, not binding). Inner-loop addressing expressions kept
// verbatim (session law: do not rewrite address exprs).
//
// SESSION LAWS (hardware-verified):
//  - 1024-thr blocks force 64 VGPR -> spill; min-waves capping VGPR<130 ->
//    spill; (512,2) safe. WRITE_SIZE>65.5MB = spill canary. (r3/5/6)
//  - Source-level rewrites of inner-loop addressing defeat the compiler's
//    schedule (r7/r9/r10/r11).
//  - XCD-affine decode: t-conv FETCH 133->69 MB; ~9% win (r8/r13 repro).
//  - setprio(1) around MFMA: t-conv -7% (r14).
//
// A-frag k-map and B-frag pack share the same k-permutation (cancels).
// C/D: col(=cout_local)=lane&31, row(=px_local)=(r&3)+8*(r>>2)+4*(lane>>5)
// ---------------------------------------------------------------------------
template<int NCHUNK>
__global__ __launch_bounds__(512, 2)
void k_conv(const short* __restrict__ in1, const short* __restrict__ in2,
            const short* __restrict__ wp, const float* __restrict__ bias,
            const float* __restrict__ alpha, short* __restrict__ out)
{
  __shared__ __align__(16) uint8_t smem[3 * 258 * 64];
  const int wg = blockIdx.x;          // 0..2047
  const int b = wg & 7;               // = XCD id under linear round-robin
  const int y = wg >> 3;              // consecutive y rows share an XCD
  const int tid = threadIdx.x;
  const int l = tid & 63;
  const int w = tid >> 6;             // wave = px tile (0..7)
  const int lm = l & 31;
  const int lh = l >> 5;

  floatx16 acc[2];  // [nblk]
  #pragma unroll
  for (int nb = 0; nb < 2; ++nb)
    #pragma unroll
    for (int r = 0; r < 16; ++r) acc[nb][r] = 0.f;

  const int xbase = w * 32 + lm;

  // staging: widx = tid + i*512, i in 0..5 -> (r 0..2, xp in 1..256, co)
  short8 stg[6];

  auto issue = [&](int q) {
    const short* __restrict__ src = ((q < 2) ? in1 : in2) + (size_t)(q & 1) * PLANE;
    #pragma unroll
    for (int i = 0; i < 6; ++i) {
      int widx = tid + i * 512;
      int r = widx >> 10;
      int xp = ((widx >> 2) & 255) + 1;
      int co = (widx & 3) << 3;
      int yy = y + r - 1;
      short8 v = {0, 0, 0, 0, 0, 0, 0, 0};
      if ((unsigned)yy < 256u)
        v = *(const short8*)(src + ((b * 256 + yy) * 256 + (xp - 1)) * 32 + co);
      stg[i] = v;
    }
  };
  auto commit = [&]() {
    #pragma unroll
    for (int i = 0; i < 6; ++i) {
      int widx = tid + i * 512;
      int r = widx >> 10;
      int xp = ((widx >> 2) & 255) + 1;
      int co = (widx & 3) << 3;
      *(short8*)(smem + ldsAddr(r, xp, co)) = stg[i];
    }
  };

  // zero the constant x-pad columns (xp=0, 257) once; chunk writes never
  // touch these bytes (ldsAddr is injective).
  if (tid < 24) {
    short8 z = {0, 0, 0, 0, 0, 0, 0, 0};
    int r = tid >> 3;
    int xp = (tid & 4) ? 257 : 0;
    int co = (tid & 3) << 3;
    *(short8*)(smem + ldsAddr(r, xp, co)) = z;
  }

  issue(0);
  commit();
  __syncthreads();

  #pragma unroll
  for (int q = 0; q < NCHUNK; ++q) {
    if (q + 1 < NCHUNK) issue(q + 1);   // loads fly under the MFMA phase

    __builtin_amdgcn_s_setprio(1);      // T5: favor MFMA waves over other
                                        // resident blocks' staging
    #pragma unroll
    for (int ky = 0; ky < 3; ++ky)
    #pragma unroll
    for (int kx = 0; kx < 3; ++kx)
    #pragma unroll
    for (int s = 0; s < 2; ++s) {
      const int ks = (q * 9 + ky * 3 + kx) * 2 + s;
      const short8 bw0 = *(const short8*)(wp + ((ks * 2 + 0) * 64 + l) * 8);
      const short8 bw1 = *(const short8*)(wp + ((ks * 2 + 1) * 64 + l) * 8);
      const int cl = s * 16 + lh * 8;
      const int xp = xbase + kx;
      const short8 av = *(const short8*)(smem + ldsAddr(ky, xp, cl));
      acc[0] = __builtin_amdgcn_mfma_f32_32x32x16_bf16(av, bw0, acc[0], 0, 0, 0);
      acc[1] = __builtin_amdgcn_mfma_f32_32x32x16_bf16(av, bw1, acc[1], 0, 0, 0);
    }
    __builtin_amdgcn_s_setprio(0);

    if (q + 1 < NCHUNK) {
      __syncthreads();   // all waves done reading LDS chunk q
      commit();
      __syncthreads();   // chunk q+1 visible
    }
  }

  const float alp = alpha[0];
  #pragma unroll
  for (int nb = 0; nb < 2; ++nb) {
    const float bs = bias[nb * 32 + lm];
    short* __restrict__ op = out + (size_t)nb * PLANE + lm;
    #pragma unroll
    for (int r = 0; r < 16; ++r) {
      int px = w * 32 + (r & 3) + ((r >> 2) << 3) + (lh << 2);
      float v = acc[nb][r] + bs;
      v = v >= 0.f ? v : alp * v;
      op[((b * 256 + y) * 256 + px) * 32] = f2b(v);
    }
  }
}

// ---------------------------------------------------------------------------
// Weight pre-pack (ks = (q*9 + tap)*2 + s).
// element (ks, nblk, lane, e) = W[cout = nblk*32 + lane&31][cin = q*32 + s*16 + 8*(lane>>5) + e]
// ---------------------------------------------------------------------------
__global__ __launch_bounds__(256)
void k_pack(const float* __restrict__ w2, const float* __restrict__ w3,
            const float* __restrict__ w4, const float* __restrict__ wf,
            short* __restrict__ wp234, short* __restrict__ wpfus)
{
  int idx = blockIdx.x * 256 + threadIdx.x;
  if (idx < 24 * 36864) {
    int conv = idx / 36864;
    int r = idx - conv * 36864;
    int which = conv >> 3, g = conv & 7;
    const float* W = (which == 0 ? w2 : which == 1 ? w3 : w4) + g * 36864;
    int ks = r >> 10;
    int nblk = (r >> 9) & 1;
    int lane = (r >> 3) & 63;
    int e = r & 7;
    int q = ks / 18, tt = ks % 18;
    int t = tt >> 1, s = tt & 1;
    int cin = q * 32 + s * 16 + ((lane >> 5) << 3) + e;
    int cout = nblk * 32 + (lane & 31);
    int ky = t / 3, kx = t % 3;
    wp234[idx] = f2b(W[((cout * 64 + cin) * 3 + ky) * 3 + kx]);
  } else {
    int idx2 = idx - 24 * 36864;
    if (idx2 >= 7 * 73728) return;
    int conv = idx2 / 73728;
    int r = idx2 - conv * 73728;
    const float* W = wf + conv * 73728;
    int ks = r >> 10;
    int nblk = (r >> 9) & 1;
    int lane = (r >> 3) & 63;
    int e = r & 7;
    int q = ks / 18, tt = ks % 18;
    int t = tt >> 1, s = tt & 1;
    int cin = q * 32 + s * 16 + ((lane >> 5) << 3) + e;
    int cout = nblk * 32 + (lane & 31);
    int ky = t / 3, kx = t % 3;
    wpfus[idx2] = f2b(W[((cout * 128 + cin) * 3 + ky) * 3 + kx]);
  }
}

// ---------------------------------------------------------------------------
// Head stage 1: sample conv (32x32, stride 32). s_all[g][b][c][gy][gx], fp32.
// ---------------------------------------------------------------------------
__global__ __launch_bounds__(256)
void k_sample(const float* __restrict__ x, const float* __restrict__ sw,
              float* __restrict__ s_all)
{
  int idx = blockIdx.x * 256 + threadIdx.x;  // 8*8*13*64 = 53248 threads
  int gx = idx & 7, gy = (idx >> 3) & 7;
  int t = idx >> 6;
  int c = t % 13; t /= 13;
  int b = t & 7, g = t >> 3;
  const float* xb = x + b * 65536 + (gy * 32) * 256 + gx * 32;
  const float* wp = sw + (g * 13 + c) * 1024;
  float acc = 0.f;
  for (int i = 0; i < 32; ++i) {
    #pragma unroll
    for (int j = 0; j < 32; ++j) acc += xb[i * 256 + j] * wp[i * 32 + j];
  }
  s_all[idx] = acc;
}

// ---------------------------------------------------------------------------
// Head stage 2: 1x1 up conv + bias, fused with depth_to_space.
// z_all[g][b][y][x] fp32, pos = (y%32)*32 + (x%32).
// ---------------------------------------------------------------------------
__global__ __launch_bounds__(256)
void k_upz(const float* __restrict__ s_all, const float* __restrict__ upw,
           const float* __restrict__ upb, float* __restrict__ z_all)
{
  int idx = blockIdx.x * 256 + threadIdx.x;  // 4194304
  int x = idx & 255, y = (idx >> 8) & 255;
  int b = (idx >> 16) & 7, g = idx >> 19;
  int pos = (y & 31) * 32 + (x & 31);
  int gy = y >> 5, gx = x >> 5;
  const float* sp = s_all + ((g * 8 + b) * 13) * 64 + gy * 8 + gx;
  const float* wp = upw + (g * 1024 + pos) * 13;
  float a = upb[g * 1024 + pos];
  #pragma unroll
  for (int c = 0; c < 13; ++c) a += wp[c] * sp[c * 64];
  z_all[idx] = a;
}

// ---------------------------------------------------------------------------
// Head stage 3: conv1 (1 -> 64, 3x3, pad 1) + PReLU, writes split-plane bf16.
// XCD-affine: b = wgid & 7 so its writes land on the XCD that fus will read.
// ---------------------------------------------------------------------------
__global__ __launch_bounds__(256)
void k_conv1(const float* __restrict__ z, const float* __restrict__ w,
             const float* __restrict__ bias, const float* __restrict__ alpha,
             short* __restrict__ out)
{
  int wg = blockIdx.x;                 // 0..2047
  int b = wg & 7;
  int y = wg >> 3;                     // 0..255
  int x = threadIdx.x;                 // 0..255
  int pid = (b * 256 + y) * 256 + x;
  float zv[9];
  #pragma unroll
  for (int t = 0; t < 9; ++t) {
    int dy = t / 3, dx = t % 3;
    int yy = y + dy - 1, xx = x + dx - 1;
    zv[t] = ((unsigned)yy < 256u && (unsigned)xx < 256u)
              ? z[b * 65536 + yy * 256 + xx] : 0.f;
  }
  float alp = alpha[0];
  #pragma unroll
  for (int c0 = 0; c0 < 64; c0 += 8) {
    short8 pack;
    #pragma unroll
    for (int e = 0; e < 8; ++e) {
      int c = c0 + e;
      float a = bias[c];
      #pragma unroll
      for (int t = 0; t < 9; ++t) a += w[c * 9 + t] * zv[t];
      a = a >= 0.f ? a : alp * a;
      pack[e] = f2b(a);
    }
    *(short8*)(out + (size_t)(c0 >> 5) * PLANE + pid * 32 + (c0 & 31)) = pack;
  }
}

// ---------------------------------------------------------------------------
// t5: 64 -> 1, 3x3, pad 1, + bias, fp32 output into d_out slice.
// XCD-affine b = wgid & 7: reads act produced on the same XCD.
// ---------------------------------------------------------------------------
__global__ __launch_bounds__(256)
void k_t5(const short* __restrict__ in, const float* __restrict__ w,
          const float* __restrict__ bias, float* __restrict__ out)
{
  int wg = blockIdx.x;                 // 0..2047
  int b = wg & 7;
  int y = wg >> 3;                     // 0..255
  int x = threadIdx.x;                 // 0..255
  float acc = bias[0];
  for (int dy = 0; dy < 3; ++dy) {
    int yy = y + dy - 1;
    if ((unsigned)yy >= 256u) continue;
    for (int dx = 0; dx < 3; ++dx) {
      int xx = x + dx - 1;
      if ((unsigned)xx >= 256u) continue;
      const int pix = (b * 256 + yy) * 256 + xx;
      #pragma unroll
      for (int c0 = 0; c0 < 64; c0 += 8) {
        short8 v = *(const short8*)(in + (size_t)(c0 >> 5) * PLANE + pix * 32 + (c0 & 31));
        #pragma unroll
        for (int e = 0; e < 8; ++e)
          acc += w[(c0 + e) * 9 + dy * 3 + dx] * b2f(v[e]);
      }
    }
  }
  out[(b * 256 + y) * 256 + x] = acc;
}

// ---------------------------------------------------------------------------
extern "C" void kernel_launch(void* const* d_in, const int* in_sizes, int n_in,
                              void* d_out, int out_size, void* d_ws, size_t ws_size,
                              hipStream_t stream) {
  const float* X   = (const float*)d_in[0];
  const float* SW  = (const float*)d_in[1];
  const float* UPW = (const float*)d_in[2];
  const float* UPB = (const float*)d_in[3];
  const float* C1W = (const float*)d_in[4];
  const float* C1B = (const float*)d_in[5];
  const float* C1A = (const float*)d_in[6];
  const float* FW  = (const float*)d_in[7];
  const float* FB  = (const float*)d_in[8];
  const float* FA  = (const float*)d_in[9];
  const float* W2  = (const float*)d_in[10];
  const float* B2  = (const float*)d_in[11];
  const float* A2  = (const float*)d_in[12];
  const float* W3  = (const float*)d_in[13];
  const float* B3  = (const float*)d_in[14];
  const float* A3  = (const float*)d_in[15];
  const float* W4  = (const float*)d_in[16];
  const float* B4  = (const float*)d_in[17];
  const float* A4  = (const float*)d_in[18];
  const float* W5  = (const float*)d_in[19];
  const float* B5  = (const float*)d_in[20];
  float* OUT = (float*)d_out;
  (void)in_sizes; (void)n_in; (void)out_size; (void)ws_size;

  uint8_t* base = (uint8_t*)d_ws;
  size_t off = 0;
  auto alloc = [&](size_t bytes) -> uint8_t* {
    uint8_t* r = base + off;
    off += (bytes + 255) & ~(size_t)255;
    return r;
  };
  const size_t ACT_ELEMS = 2ull * PLANE;               // 33,554,432 bf16
  short* act[3];
  for (int i = 0; i < 3; ++i) act[i] = (short*)alloc(ACT_ELEMS * 2);
  float* z_all = (float*)alloc(4194304ull * 4);
  float* s_all = (float*)alloc(53248ull * 4);
  short* wp234 = (short*)alloc(884736ull * 2);
  short* wpfus = (short*)alloc(516096ull * 2);

  k_pack<<<dim3(5472), dim3(256), 0, stream>>>(W2, W3, W4, FW, wp234, wpfus);
  k_sample<<<dim3(208), dim3(256), 0, stream>>>(X, SW, s_all);
  k_upz<<<dim3(16384), dim3(256), 0, stream>>>(s_all, UPW, UPB, z_all);

  int cur = 0, A = 1, B = 2;
  // head(0) -> cur
  k_conv1<<<dim3(2048), dim3(256), 0, stream>>>(z_all, C1W, C1B, C1A, act[cur]);

  for (int m = 0; m < 8; ++m) {
    const short* wp_t2 = wp234 + (0 * 8 + m) * 36864;
    const short* wp_t3 = wp234 + (1 * 8 + m) * 36864;
    const short* wp_t4 = wp234 + (2 * 8 + m) * 36864;

    k_conv<2><<<dim3(2048), dim3(512), 0, stream>>>(
        act[cur], act[cur], wp_t2, B2 + m * 64, A2 + m, act[A]);
    k_conv<2><<<dim3(2048), dim3(512), 0, stream>>>(
        act[A], act[A], wp_t3, B3 + m * 64, A3 + m, act[B]);
    k_conv<2><<<dim3(2048), dim3(512), 0, stream>>>(
        act[B], act[B], wp_t4, B4 + m * 64, A4 + m, act[A]);
    k_t5<<<dim3(2048), dim3(256), 0, stream>>>(
        act[A], W5 + m * 576, B5 + m, OUT + (size_t)m * 524288);

    if (m < 7) {
      // head(m+1) -> act[B] (free after t4 consumed it)
      k_conv1<<<dim3(2048), dim3(256), 0, stream>>>(
          z_all + (size_t)(m + 1) * 524288, C1W + (m + 1) * 576,
          C1B + (m + 1) * 64, C1A + (m + 1), act[B]);
      // fus(cur, head) -> act[A] (free after t5 consumed it)
      k_conv<4><<<dim3(2048), dim3(512), 0, stream>>>(
          act[cur], act[B], wpfus + m * 73728, FB + m * 64, FA + m, act[A]);
      int tmp = cur; cur = A; A = tmp;  // new cur = fus output
    }
  }
}

// Round 16
// 2665.736 us; speedup vs baseline: 1.3470x; 1.0910x over previous
//
#include <hip/hip_runtime.h>
#include <stdint.h>

typedef __attribute__((ext_vector_type(8))) short short8;
typedef __attribute__((ext_vector_type(16))) float floatx16;

#define PLANE16 8388608  // 8*256*256*16 elems: one 16-channel plane

__device__ __forceinline__ float b2f(short s) {
  union { uint32_t u; float f; } v; v.u = ((uint32_t)(uint16_t)s) << 16; return v.f;
}
__device__ __forceinline__ short f2b(float f) {
  union { float f; uint32_t u; } v; v.f = f;
  uint32_t r = (v.u + 0x7FFFu + ((v.u >> 16) & 1u)) >> 16;
  return (short)r;
}

// LDS tile: [3 rows][258 xp][16 ch] bf16, 32 B per (r,xp) row. Swizzle XORs
// only byte bit 4 (16-B half within the row) with xp2^xp3^xp4 -> injective
// half-swap (R10-validated formula); same fn on write & read.
__device__ __forceinline__ uint32_t ldsA(int r, int xp, int c) {
  uint32_t byte = ((uint32_t)(r * 258 + xp) << 5) + ((uint32_t)c << 1);
  byte ^= (uint32_t)((((xp >> 2) ^ (xp >> 3) ^ (xp >> 4)) & 1) << 4);
  return byte;
}

// ---------------------------------------------------------------------------
// Main MFMA conv: 3x3, pad 1, C_in = 16*NC16 (chunks 0-3 = planes of in1,
// 4-7 = planes of in2), C_out = 64, PReLU.
// Activations: 16-ch planes NHWC bf16 [4][8][256][256][16] (coalesced chunk
// loads: one chunk = one contiguous 32 B/px plane).
// ROUND-16: R15 structure (1-row block, 8 waves, wave w owns px tile w) with
// 16-ch chunks -> LDS 24.8 KB -> 4 blocks/CU (32 waves = HW max, was 3/24).
// 18 MFMA/chunk, NC16 chunks; same total MFMA as R15.
//
// SESSION LAWS (hardware-verified):
//  - 1024-thr blocks force 64 VGPR -> spill; min-waves capping VGPR<130 ->
//    spill; (512,2) safe. WRITE_SIZE>65.5MB = spill canary. (r3/5/6)
//  - Do not rewrite inner-loop addressing exprs (r7/r9/r10/r11).
//  - XCD-affine decode: halo from same-XCD L2, FETCH -> ideal (r8/r13).
//  - setprio(1) around MFMA: t-conv -7% (r14).
//  - Occupancy is the live lever: 2->3 blocks/CU gave -6% total (r15).
//
// A-frag k-map (k = 8*(l>>5)+e, cin = c16*16+k) and B-pack share the same
// permutation (cancels).
// C/D: col(=cout_local)=lane&31, row(=px_local)=(r&3)+8*(r>>2)+4*(lane>>5)
// ---------------------------------------------------------------------------
template<int NC16>
__global__ __launch_bounds__(512, 2)
void k_conv(const short* __restrict__ in1, const short* __restrict__ in2,
            const short* __restrict__ wp, const float* __restrict__ bias,
            const float* __restrict__ alpha, short* __restrict__ out)
{
  __shared__ __align__(16) uint8_t smem[3 * 258 * 32];
  const int wg = blockIdx.x;          // 0..2047
  const int b = wg & 7;               // = XCD id under linear round-robin
  const int y = wg >> 3;              // consecutive y rows share an XCD
  const int tid = threadIdx.x;
  const int l = tid & 63;
  const int w = tid >> 6;             // wave = px tile (0..7)
  const int lm = l & 31;
  const int lh = l >> 5;

  floatx16 acc[2];  // [nblk]
  #pragma unroll
  for (int nb = 0; nb < 2; ++nb)
    #pragma unroll
    for (int r = 0; r < 16; ++r) acc[nb][r] = 0.f;

  const int xbase = w * 32 + lm;

  // staging: widx = tid + i*512 in [0,1536): r = widx>>9, xp = ((widx&511)>>1)+1,
  // half = widx&1. Exactly 3 16-B items/thread.
  short8 stg[3];

  auto issue = [&](int c16) {
    const short* __restrict__ src =
        ((c16 < 4) ? in1 : in2) + (size_t)(c16 & 3) * PLANE16;
    #pragma unroll
    for (int i = 0; i < 3; ++i) {
      int widx = tid + i * 512;
      int r = widx >> 9;
      int rem = widx & 511;
      int xp = (rem >> 1) + 1;
      int half = rem & 1;
      int yy = y + r - 1;
      short8 v = {0, 0, 0, 0, 0, 0, 0, 0};
      if ((unsigned)yy < 256u)
        v = *(const short8*)(src + ((b * 256 + yy) * 256 + (xp - 1)) * 16 + half * 8);
      stg[i] = v;
    }
  };
  auto commit = [&]() {
    #pragma unroll
    for (int i = 0; i < 3; ++i) {
      int widx = tid + i * 512;
      int r = widx >> 9;
      int rem = widx & 511;
      int xp = (rem >> 1) + 1;
      int half = rem & 1;
      *(short8*)(smem + ldsA(r, xp, half * 8)) = stg[i];
    }
  };

  // zero the constant x-pad columns (xp=0, 257) once; chunk commits never
  // touch these bytes (ldsA is injective, swizzle stays within the row).
  if (tid < 12) {
    short8 z = {0, 0, 0, 0, 0, 0, 0, 0};
    int r = tid >> 2;
    int xp = (tid & 2) ? 257 : 0;
    int half = tid & 1;
    *(short8*)(smem + ldsA(r, xp, half * 8)) = z;
  }

  issue(0);
  commit();
  __syncthreads();

  #pragma unroll
  for (int c16 = 0; c16 < NC16; ++c16) {
    if (c16 + 1 < NC16) issue(c16 + 1);   // loads fly under the MFMA phase

    __builtin_amdgcn_s_setprio(1);        // T5: favor MFMA waves over other
                                          // resident blocks' staging
    #pragma unroll
    for (int ky = 0; ky < 3; ++ky)
    #pragma unroll
    for (int kx = 0; kx < 3; ++kx) {
      const int ks = c16 * 9 + ky * 3 + kx;
      const short8 bw0 = *(const short8*)(wp + ((ks * 2 + 0) * 64 + l) * 8);
      const short8 bw1 = *(const short8*)(wp + ((ks * 2 + 1) * 64 + l) * 8);
      const int cl = lh * 8;
      const int xp = xbase + kx;
      const short8 av = *(const short8*)(smem + ldsA(ky, xp, cl));
      acc[0] = __builtin_amdgcn_mfma_f32_32x32x16_bf16(av, bw0, acc[0], 0, 0, 0);
      acc[1] = __builtin_amdgcn_mfma_f32_32x32x16_bf16(av, bw1, acc[1], 0, 0, 0);
    }
    __builtin_amdgcn_s_setprio(0);

    if (c16 + 1 < NC16) {
      __syncthreads();   // all waves done reading LDS chunk c16
      commit();
      __syncthreads();   // chunk c16+1 visible
    }
  }

  const float alp = alpha[0];
  #pragma unroll
  for (int nb = 0; nb < 2; ++nb) {
    const float bs = bias[nb * 32 + lm];
    short* __restrict__ op = out + (size_t)(nb * 2 + (lm >> 4)) * PLANE16 + (lm & 15);
    #pragma unroll
    for (int r = 0; r < 16; ++r) {
      int px = w * 32 + (r & 3) + ((r >> 2) << 3) + (lh << 2);
      float v = acc[nb][r] + bs;
      v = v >= 0.f ? v : alp * v;
      op[((b * 256 + y) * 256 + px) * 16] = f2b(v);
    }
  }
}

// ---------------------------------------------------------------------------
// Weight pre-pack, c16-major (ks16 = c16*9 + tap).
// element (ks16, nblk, lane, e) =
//   W[cout = nblk*32 + lane&31][cin = c16*16 + 8*(lane>>5) + e][ky][kx]
// ---------------------------------------------------------------------------
__global__ __launch_bounds__(256)
void k_pack(const float* __restrict__ w2, const float* __restrict__ w3,
            const float* __restrict__ w4, const float* __restrict__ wf,
            short* __restrict__ wp234, short* __restrict__ wpfus)
{
  int idx = blockIdx.x * 256 + threadIdx.x;
  if (idx < 24 * 36864) {
    int conv = idx / 36864;
    int r = idx - conv * 36864;
    int which = conv >> 3, g = conv & 7;
    const float* W = (which == 0 ? w2 : which == 1 ? w3 : w4) + g * 36864;
    int ks = r >> 10;                 // [0,36) = c16*9 + t
    int nblk = (r >> 9) & 1;
    int lane = (r >> 3) & 63;
    int e = r & 7;
    int c16 = ks / 9;
    int t = ks - c16 * 9;
    int cin = c16 * 16 + ((lane >> 5) << 3) + e;
    int cout = nblk * 32 + (lane & 31);
    int ky = t / 3, kx = t % 3;
    wp234[idx] = f2b(W[((cout * 64 + cin) * 3 + ky) * 3 + kx]);
  } else {
    int idx2 = idx - 24 * 36864;
    if (idx2 >= 7 * 73728) return;
    int conv = idx2 / 73728;
    int r = idx2 - conv * 73728;
    const float* W = wf + conv * 73728;
    int ks = r >> 10;                 // [0,72)
    int nblk = (r >> 9) & 1;
    int lane = (r >> 3) & 63;
    int e = r & 7;
    int c16 = ks / 9;
    int t = ks - c16 * 9;
    int cin = c16 * 16 + ((lane >> 5) << 3) + e;
    int cout = nblk * 32 + (lane & 31);
    int ky = t / 3, kx = t % 3;
    wpfus[idx2] = f2b(W[((cout * 128 + cin) * 3 + ky) * 3 + kx]);
  }
}

// ---------------------------------------------------------------------------
// Head stage 1: sample conv (32x32, stride 32). s_all[g][b][c][gy][gx], fp32.
// ---------------------------------------------------------------------------
__global__ __launch_bounds__(256)
void k_sample(const float* __restrict__ x, const float* __restrict__ sw,
              float* __restrict__ s_all)
{
  int idx = blockIdx.x * 256 + threadIdx.x;  // 8*8*13*64 = 53248 threads
  int gx = idx & 7, gy = (idx >> 3) & 7;
  int t = idx >> 6;
  int c = t % 13; t /= 13;
  int b = t & 7, g = t >> 3;
  const float* xb = x + b * 65536 + (gy * 32) * 256 + gx * 32;
  const float* wp = sw + (g * 13 + c) * 1024;
  float acc = 0.f;
  for (int i = 0; i < 32; ++i) {
    #pragma unroll
    for (int j = 0; j < 32; ++j) acc += xb[i * 256 + j] * wp[i * 32 + j];
  }
  s_all[idx] = acc;
}

// ---------------------------------------------------------------------------
// Head stage 2: 1x1 up conv + bias, fused with depth_to_space.
// z_all[g][b][y][x] fp32, pos = (y%32)*32 + (x%32).
// ---------------------------------------------------------------------------
__global__ __launch_bounds__(256)
void k_upz(const float* __restrict__ s_all, const float* __restrict__ upw,
           const float* __restrict__ upb, float* __restrict__ z_all)
{
  int idx = blockIdx.x * 256 + threadIdx.x;  // 4194304
  int x = idx & 255, y = (idx >> 8) & 255;
  int b = (idx >> 16) & 7, g = idx >> 19;
  int pos = (y & 31) * 32 + (x & 31);
  int gy = y >> 5, gx = x >> 5;
  const float* sp = s_all + ((g * 8 + b) * 13) * 64 + gy * 8 + gx;
  const float* wp = upw + (g * 1024 + pos) * 13;
  float a = upb[g * 1024 + pos];
  #pragma unroll
  for (int c = 0; c < 13; ++c) a += wp[c] * sp[c * 64];
  z_all[idx] = a;
}

// ---------------------------------------------------------------------------
// Head stage 3: conv1 (1 -> 64, 3x3, pad 1) + PReLU, writes 16-ch planes.
// XCD-affine: b = wgid & 7 so its writes land on the XCD that fus will read.
// ---------------------------------------------------------------------------
__global__ __launch_bounds__(256)
void k_conv1(const float* __restrict__ z, const float* __restrict__ w,
             const float* __restrict__ bias, const float* __restrict__ alpha,
             short* __restrict__ out)
{
  int wg = blockIdx.x;                 // 0..2047
  int b = wg & 7;
  int y = wg >> 3;                     // 0..255
  int x = threadIdx.x;                 // 0..255
  int pid = (b * 256 + y) * 256 + x;
  float zv[9];
  #pragma unroll
  for (int t = 0; t < 9; ++t) {
    int dy = t / 3, dx = t % 3;
    int yy = y + dy - 1, xx = x + dx - 1;
    zv[t] = ((unsigned)yy < 256u && (unsigned)xx < 256u)
              ? z[b * 65536 + yy * 256 + xx] : 0.f;
  }
  float alp = alpha[0];
  #pragma unroll
  for (int c0 = 0; c0 < 64; c0 += 8) {
    short8 pack;
    #pragma unroll
    for (int e = 0; e < 8; ++e) {
      int c = c0 + e;
      float a = bias[c];
      #pragma unroll
      for (int t = 0; t < 9; ++t) a += w[c * 9 + t] * zv[t];
      a = a >= 0.f ? a : alp * a;
      pack[e] = f2b(a);
    }
    *(short8*)(out + (size_t)(c0 >> 4) * PLANE16 + pid * 16 + (c0 & 8)) = pack;
  }
}

// ---------------------------------------------------------------------------
// t5: 64 -> 1, 3x3, pad 1, + bias, fp32 output into d_out slice.
// XCD-affine b = wgid & 7: reads act produced on the same XCD.
// ---------------------------------------------------------------------------
__global__ __launch_bounds__(256)
void k_t5(const short* __restrict__ in, const float* __restrict__ w,
          const float* __restrict__ bias, float* __restrict__ out)
{
  int wg = blockIdx.x;                 // 0..2047
  int b = wg & 7;
  int y = wg >> 3;                     // 0..255
  int x = threadIdx.x;                 // 0..255
  float acc = bias[0];
  for (int dy = 0; dy < 3; ++dy) {
    int yy = y + dy - 1;
    if ((unsigned)yy >= 256u) continue;
    for (int dx = 0; dx < 3; ++dx) {
      int xx = x + dx - 1;
      if ((unsigned)xx >= 256u) continue;
      const int pix = (b * 256 + yy) * 256 + xx;
      #pragma unroll
      for (int c0 = 0; c0 < 64; c0 += 8) {
        short8 v = *(const short8*)(in + (size_t)(c0 >> 4) * PLANE16 + pix * 16 + (c0 & 8));
        #pragma unroll
        for (int e = 0; e < 8; ++e)
          acc += w[(c0 + e) * 9 + dy * 3 + dx] * b2f(v[e]);
      }
    }
  }
  out[(b * 256 + y) * 256 + x] = acc;
}

// ---------------------------------------------------------------------------
extern "C" void kernel_launch(void* const* d_in, const int* in_sizes, int n_in,
                              void* d_out, int out_size, void* d_ws, size_t ws_size,
                              hipStream_t stream) {
  const float* X   = (const float*)d_in[0];
  const float* SW  = (const float*)d_in[1];
  const float* UPW = (const float*)d_in[2];
  const float* UPB = (const float*)d_in[3];
  const float* C1W = (const float*)d_in[4];
  const float* C1B = (const float*)d_in[5];
  const float* C1A = (const float*)d_in[6];
  const float* FW  = (const float*)d_in[7];
  const float* FB  = (const float*)d_in[8];
  const float* FA  = (const float*)d_in[9];
  const float* W2  = (const float*)d_in[10];
  const float* B2  = (const float*)d_in[11];
  const float* A2  = (const float*)d_in[12];
  const float* W3  = (const float*)d_in[13];
  const float* B3  = (const float*)d_in[14];
  const float* A3  = (const float*)d_in[15];
  const float* W4  = (const float*)d_in[16];
  const float* B4  = (const float*)d_in[17];
  const float* A4  = (const float*)d_in[18];
  const float* W5  = (const float*)d_in[19];
  const float* B5  = (const float*)d_in[20];
  float* OUT = (float*)d_out;
  (void)in_sizes; (void)n_in; (void)out_size; (void)ws_size;

  uint8_t* base = (uint8_t*)d_ws;
  size_t off = 0;
  auto alloc = [&](size_t bytes) -> uint8_t* {
    uint8_t* r = base + off;
    off += (bytes + 255) & ~(size_t)255;
    return r;
  };
  const size_t ACT_ELEMS = 4ull * PLANE16;             // 33,554,432 bf16
  short* act[3];
  for (int i = 0; i < 3; ++i) act[i] = (short*)alloc(ACT_ELEMS * 2);
  float* z_all = (float*)alloc(4194304ull * 4);
  float* s_all = (float*)alloc(53248ull * 4);
  short* wp234 = (short*)alloc(884736ull * 2);
  short* wpfus = (short*)alloc(516096ull * 2);

  k_pack<<<dim3(5472), dim3(256), 0, stream>>>(W2, W3, W4, FW, wp234, wpfus);
  k_sample<<<dim3(208), dim3(256), 0, stream>>>(X, SW, s_all);
  k_upz<<<dim3(16384), dim3(256), 0, stream>>>(s_all, UPW, UPB, z_all);

  int cur = 0, A = 1, B = 2;
  // head(0) -> cur
  k_conv1<<<dim3(2048), dim3(256), 0, stream>>>(z_all, C1W, C1B, C1A, act[cur]);

  for (int m = 0; m < 8; ++m) {
    const short* wp_t2 = wp234 + (0 * 8 + m) * 36864;
    const short* wp_t3 = wp234 + (1 * 8 + m) * 36864;
    const short* wp_t4 = wp234 + (2 * 8 + m) * 36864;

    k_conv<4><<<dim3(2048), dim3(512), 0, stream>>>(
        act[cur], act[cur], wp_t2, B2 + m * 64, A2 + m, act[A]);
    k_conv<4><<<dim3(2048), dim3(512), 0, stream>>>(
        act[A], act[A], wp_t3, B3 + m * 64, A3 + m, act[B]);
    k_conv<4><<<dim3(2048), dim3(512), 0, stream>>>(
        act[B], act[B], wp_t4, B4 + m * 64, A4 + m, act[A]);
    k_t5<<<dim3(2048), dim3(256), 0, stream>>>(
        act[A], W5 + m * 576, B5 + m, OUT + (size_t)m * 524288);

    if (m < 7) {
      // head(m+1) -> act[B] (free after t4 consumed it)
      k_conv1<<<dim3(2048), dim3(256), 0, stream>>>(
          z_all + (size_t)(m + 1) * 524288, C1W + (m + 1) * 576,
          C1B + (m + 1) * 64, C1A + (m + 1), act[B]);
      // fus(cur, head) -> act[A] (free after t5 consumed it)
      k_conv<8><<<dim3(2048), dim3(512), 0, stream>>>(
          act[cur], act[B], wpfus + m * 73728, FB + m * 64, FA + m, act[A]);
      int tmp = cur; cur = A; A = tmp;  // new cur = fus output
    }
  }
}

// Round 17
// 2649.613 us; speedup vs baseline: 1.3552x; 1.0061x over previous
//
#include <hip/hip_runtime.h>
#include <stdint.h>

typedef __attribute__((ext_vector_type(8))) short short8;
typedef __attribute__((ext_vector_type(16))) float floatx16;

#define PLANE16 8388608  // 8*256*256*16 elems: one 16-channel plane
#define LDSBUF 24768     // 3*258*32 bytes: one 16-ch chunk tile

__device__ __forceinline__ float b2f(short s) {
  union { uint32_t u; float f; } v; v.u = ((uint32_t)(uint16_t)s) << 16; return v.f;
}
__device__ __forceinline__ short f2b(float f) {
  union { float f; uint32_t u; } v; v.f = f;
  uint32_t r = (v.u + 0x7FFFu + ((v.u >> 16) & 1u)) >> 16;
  return (short)r;
}

// LDS tile: [buf][3 rows][258 xp][16 ch] bf16, 32 B per (r,xp) row. Swizzle
// XORs only byte bit 4 (16-B half within the row) with xp2^xp3^xp4 ->
// injective half-swap (validated R10/R16); same fn on write & read.
// buf index is compile-time-constant under the unrolled chunk loop.
__device__ __forceinline__ uint32_t ldsA(int buf, int r, int xp, int c) {
  uint32_t byte = (uint32_t)buf * LDSBUF
                + ((uint32_t)(r * 258 + xp) << 5) + ((uint32_t)c << 1);
  byte ^= (uint32_t)((((xp >> 2) ^ (xp >> 3) ^ (xp >> 4)) & 1) << 4);
  return byte;
}

// ---------------------------------------------------------------------------
// Main MFMA conv: 3x3, pad 1, C_in = 16*NC16 (chunks 0-3 = planes of in1,
// 4-7 = planes of in2), C_out = 64, PReLU.
// Activations: 16-ch planes NHWC bf16 [4][8][256][256][16].
// R16 structure: 1-row block, 8 waves, wave w owns px tile w, 18 MFMA/chunk.
// ROUND-17: two LDS buffers (2 x 24.8 KB -> 3 blocks/CU, was 4) -> ONE
// barrier per chunk (was 2): compute from buf[c&1], commit into buf[(c+1)&1]
// (prev barrier guarantees chunk c-1 readers are done; chunk-c readers use
// the other buffer), then sync. Barriers per t-conv 7 -> 4.
//
// SESSION LAWS (hardware-verified):
//  - 1024-thr blocks force 64 VGPR -> spill; min-waves capping VGPR<130 ->
//    spill; (512,2) safe. WRITE_SIZE>65.5MB = spill canary. (r3/5/6)
//  - Do not rewrite inner-loop addressing exprs (r7/r9/r11).
//  - XCD-affine decode: halo from same-XCD L2 (r8/r13). setprio: -7% (r14).
//  - Occupancy ladder: 2->3->4 blocks/CU gave -6%/-8% (r15/r16).
//
// A-frag k-map (k = 8*(l>>5)+e, cin = c16*16+k) and B-pack share the same
// permutation (cancels).
// C/D: col(=cout_local)=lane&31, row(=px_local)=(r&3)+8*(r>>2)+4*(lane>>5)
// ---------------------------------------------------------------------------
template<int NC16>
__global__ __launch_bounds__(512, 2)
void k_conv(const short* __restrict__ in1, const short* __restrict__ in2,
            const short* __restrict__ wp, const float* __restrict__ bias,
            const float* __restrict__ alpha, short* __restrict__ out)
{
  __shared__ __align__(16) uint8_t smem[2 * LDSBUF];
  const int wg = blockIdx.x;          // 0..2047
  const int b = wg & 7;               // = XCD id under linear round-robin
  const int y = wg >> 3;              // consecutive y rows share an XCD
  const int tid = threadIdx.x;
  const int l = tid & 63;
  const int w = tid >> 6;             // wave = px tile (0..7)
  const int lm = l & 31;
  const int lh = l >> 5;

  floatx16 acc[2];  // [nblk]
  #pragma unroll
  for (int nb = 0; nb < 2; ++nb)
    #pragma unroll
    for (int r = 0; r < 16; ++r) acc[nb][r] = 0.f;

  const int xbase = w * 32 + lm;

  // staging: widx = tid + i*512 in [0,1536): r = widx>>9, xp = ((widx&511)>>1)+1,
  // half = widx&1. Exactly 3 16-B items/thread.
  short8 stg[3];

  auto issue = [&](int c16) {
    const short* __restrict__ src =
        ((c16 < 4) ? in1 : in2) + (size_t)(c16 & 3) * PLANE16;
    #pragma unroll
    for (int i = 0; i < 3; ++i) {
      int widx = tid + i * 512;
      int r = widx >> 9;
      int rem = widx & 511;
      int xp = (rem >> 1) + 1;
      int half = rem & 1;
      int yy = y + r - 1;
      short8 v = {0, 0, 0, 0, 0, 0, 0, 0};
      if ((unsigned)yy < 256u)
        v = *(const short8*)(src + ((b * 256 + yy) * 256 + (xp - 1)) * 16 + half * 8);
      stg[i] = v;
    }
  };
  auto commit = [&](int buf) {
    #pragma unroll
    for (int i = 0; i < 3; ++i) {
      int widx = tid + i * 512;
      int r = widx >> 9;
      int rem = widx & 511;
      int xp = (rem >> 1) + 1;
      int half = rem & 1;
      *(short8*)(smem + ldsA(buf, r, xp, half * 8)) = stg[i];
    }
  };

  // zero the constant x-pad columns (xp=0, 257) of BOTH buffers once; chunk
  // commits never touch these bytes (ldsA is injective within the row).
  if (tid < 24) {
    short8 z = {0, 0, 0, 0, 0, 0, 0, 0};
    int buf = tid >> 4;          // wait: 24 items = 2 buf * 3 r * 2 xp * 2 half
    int rem = tid & 15;          // buf 0: tid 0..15 wait no
    // decode: tid in [0,24): buf = tid/12, rr = (tid%12)/4, xp/half from low bits
    buf = tid / 12;
    int t12 = tid - buf * 12;
    int r = t12 >> 2;
    int xp = (t12 & 2) ? 257 : 0;
    int half = t12 & 1;
    *(short8*)(smem + ldsA(buf, r, xp, half * 8)) = z;
  }

  issue(0);
  commit(0);
  __syncthreads();

  #pragma unroll
  for (int c16 = 0; c16 < NC16; ++c16) {
    const int p = c16 & 1;
    if (c16 + 1 < NC16) issue(c16 + 1);   // loads fly under the MFMA phase

    __builtin_amdgcn_s_setprio(1);        // T5: favor MFMA waves over other
                                          // resident blocks' staging
    #pragma unroll
    for (int ky = 0; ky < 3; ++ky)
    #pragma unroll
    for (int kx = 0; kx < 3; ++kx) {
      const int ks = c16 * 9 + ky * 3 + kx;
      const short8 bw0 = *(const short8*)(wp + ((ks * 2 + 0) * 64 + l) * 8);
      const short8 bw1 = *(const short8*)(wp + ((ks * 2 + 1) * 64 + l) * 8);
      const int cl = lh * 8;
      const int xp = xbase + kx;
      const short8 av = *(const short8*)(smem + ldsA(p, ky, xp, cl));
      acc[0] = __builtin_amdgcn_mfma_f32_32x32x16_bf16(av, bw0, acc[0], 0, 0, 0);
      acc[1] = __builtin_amdgcn_mfma_f32_32x32x16_bf16(av, bw1, acc[1], 0, 0, 0);
    }
    __builtin_amdgcn_s_setprio(0);

    if (c16 + 1 < NC16) {
      commit(p ^ 1);     // other buffer: chunk-c readers unaffected; chunk
                         // c-1 readers finished at the previous barrier
      __syncthreads();   // one barrier per chunk
    }
  }

  const float alp = alpha[0];
  #pragma unroll
  for (int nb = 0; nb < 2; ++nb) {
    const float bs = bias[nb * 32 + lm];
    short* __restrict__ op = out + (size_t)(nb * 2 + (lm >> 4)) * PLANE16 + (lm & 15);
    #pragma unroll
    for (int r = 0; r < 16; ++r) {
      int px = w * 32 + (r & 3) + ((r >> 2) << 3) + (lh << 2);
      float v = acc[nb][r] + bs;
      v = v >= 0.f ? v : alp * v;
      op[((b * 256 + y) * 256 + px) * 16] = f2b(v);
    }
  }
}

// ---------------------------------------------------------------------------
// Weight pre-pack, c16-major (ks16 = c16*9 + tap).
// element (ks16, nblk, lane, e) =
//   W[cout = nblk*32 + lane&31][cin = c16*16 + 8*(lane>>5) + e][ky][kx]
// ---------------------------------------------------------------------------
__global__ __launch_bounds__(256)
void k_pack(const float* __restrict__ w2, const float* __restrict__ w3,
            const float* __restrict__ w4, const float* __restrict__ wf,
            short* __restrict__ wp234, short* __restrict__ wpfus)
{
  int idx = blockIdx.x * 256 + threadIdx.x;
  if (idx < 24 * 36864) {
    int conv = idx / 36864;
    int r = idx - conv * 36864;
    int which = conv >> 3, g = conv & 7;
    const float* W = (which == 0 ? w2 : which == 1 ? w3 : w4) + g * 36864;
    int ks = r >> 10;                 // [0,36) = c16*9 + t
    int nblk = (r >> 9) & 1;
    int lane = (r >> 3) & 63;
    int e = r & 7;
    int c16 = ks / 9;
    int t = ks - c16 * 9;
    int cin = c16 * 16 + ((lane >> 5) << 3) + e;
    int cout = nblk * 32 + (lane & 31);
    int ky = t / 3, kx = t % 3;
    wp234[idx] = f2b(W[((cout * 64 + cin) * 3 + ky) * 3 + kx]);
  } else {
    int idx2 = idx - 24 * 36864;
    if (idx2 >= 7 * 73728) return;
    int conv = idx2 / 73728;
    int r = idx2 - conv * 73728;
    const float* W = wf + conv * 73728;
    int ks = r >> 10;                 // [0,72)
    int nblk = (r >> 9) & 1;
    int lane = (r >> 3) & 63;
    int e = r & 7;
    int c16 = ks / 9;
    int t = ks - c16 * 9;
    int cin = c16 * 16 + ((lane >> 5) << 3) + e;
    int cout = nblk * 32 + (lane & 31);
    int ky = t / 3, kx = t % 3;
    wpfus[idx2] = f2b(W[((cout * 128 + cin) * 3 + ky) * 3 + kx]);
  }
}

// ---------------------------------------------------------------------------
// Head stage 1: sample conv (32x32, stride 32). s_all[g][b][c][gy][gx], fp32.
// ---------------------------------------------------------------------------
__global__ __launch_bounds__(256)
void k_sample(const float* __restrict__ x, const float* __restrict__ sw,
              float* __restrict__ s_all)
{
  int idx = blockIdx.x * 256 + threadIdx.x;  // 8*8*13*64 = 53248 threads
  int gx = idx & 7, gy = (idx >> 3) & 7;
  int t = idx >> 6;
  int c = t % 13; t /= 13;
  int b = t & 7, g = t >> 3;
  const float* xb = x + b * 65536 + (gy * 32) * 256 + gx * 32;
  const float* wp = sw + (g * 13 + c) * 1024;
  float acc = 0.f;
  for (int i = 0; i < 32; ++i) {
    #pragma unroll
    for (int j = 0; j < 32; ++j) acc += xb[i * 256 + j] * wp[i * 32 + j];
  }
  s_all[idx] = acc;
}

// ---------------------------------------------------------------------------
// Head stage 2: 1x1 up conv + bias, fused with depth_to_space.
// z_all[g][b][y][x] fp32, pos = (y%32)*32 + (x%32).
// ---------------------------------------------------------------------------
__global__ __launch_bounds__(256)
void k_upz(const float* __restrict__ s_all, const float* __restrict__ upw,
           const float* __restrict__ upb, float* __restrict__ z_all)
{
  int idx = blockIdx.x * 256 + threadIdx.x;  // 4194304
  int x = idx & 255, y = (idx >> 8) & 255;
  int b = (idx >> 16) & 7, g = idx >> 19;
  int pos = (y & 31) * 32 + (x & 31);
  int gy = y >> 5, gx = x >> 5;
  const float* sp = s_all + ((g * 8 + b) * 13) * 64 + gy * 8 + gx;
  const float* wp = upw + (g * 1024 + pos) * 13;
  float a = upb[g * 1024 + pos];
  #pragma unroll
  for (int c = 0; c < 13; ++c) a += wp[c] * sp[c * 64];
  z_all[idx] = a;
}

// ---------------------------------------------------------------------------
// Head stage 3: conv1 (1 -> 64, 3x3, pad 1) + PReLU, writes 16-ch planes.
// XCD-affine: b = wgid & 7 so its writes land on the XCD that fus will read.
// ---------------------------------------------------------------------------
__global__ __launch_bounds__(256)
void k_conv1(const float* __restrict__ z, const float* __restrict__ w,
             const float* __restrict__ bias, const float* __restrict__ alpha,
             short* __restrict__ out)
{
  int wg = blockIdx.x;                 // 0..2047
  int b = wg & 7;
  int y = wg >> 3;                     // 0..255
  int x = threadIdx.x;                 // 0..255
  int pid = (b * 256 + y) * 256 + x;
  float zv[9];
  #pragma unroll
  for (int t = 0; t < 9; ++t) {
    int dy = t / 3, dx = t % 3;
    int yy = y + dy - 1, xx = x + dx - 1;
    zv[t] = ((unsigned)yy < 256u && (unsigned)xx < 256u)
              ? z[b * 65536 + yy * 256 + xx] : 0.f;
  }
  float alp = alpha[0];
  #pragma unroll
  for (int c0 = 0; c0 < 64; c0 += 8) {
    short8 pack;
    #pragma unroll
    for (int e = 0; e < 8; ++e) {
      int c = c0 + e;
      float a = bias[c];
      #pragma unroll
      for (int t = 0; t < 9; ++t) a += w[c * 9 + t] * zv[t];
      a = a >= 0.f ? a : alp * a;
      pack[e] = f2b(a);
    }
    *(short8*)(out + (size_t)(c0 >> 4) * PLANE16 + pid * 16 + (c0 & 8)) = pack;
  }
}

// ---------------------------------------------------------------------------
// t5: 64 -> 1, 3x3, pad 1, + bias, fp32 output into d_out slice.
// XCD-affine b = wgid & 7: reads act produced on the same XCD.
// ---------------------------------------------------------------------------
__global__ __launch_bounds__(256)
void k_t5(const short* __restrict__ in, const float* __restrict__ w,
          const float* __restrict__ bias, float* __restrict__ out)
{
  int wg = blockIdx.x;                 // 0..2047
  int b = wg & 7;
  int y = wg >> 3;                     // 0..255
  int x = threadIdx.x;                 // 0..255
  float acc = bias[0];
  for (int dy = 0; dy < 3; ++dy) {
    int yy = y + dy - 1;
    if ((unsigned)yy >= 256u) continue;
    for (int dx = 0; dx < 3; ++dx) {
      int xx = x + dx - 1;
      if ((unsigned)xx >= 256u) continue;
      const int pix = (b * 256 + yy) * 256 + xx;
      #pragma unroll
      for (int c0 = 0; c0 < 64; c0 += 8) {
        short8 v = *(const short8*)(in + (size_t)(c0 >> 4) * PLANE16 + pix * 16 + (c0 & 8));
        #pragma unroll
        for (int e = 0; e < 8; ++e)
          acc += w[(c0 + e) * 9 + dy * 3 + dx] * b2f(v[e]);
      }
    }
  }
  out[(b * 256 + y) * 256 + x] = acc;
}

// ---------------------------------------------------------------------------
extern "C" void kernel_launch(void* const* d_in, const int* in_sizes, int n_in,
                              void* d_out, int out_size, void* d_ws, size_t ws_size,
                              hipStream_t stream) {
  const float* X   = (const float*)d_in[0];
  const float* SW  = (const float*)d_in[1];
  const float* UPW = (const float*)d_in[2];
  const float* UPB = (const float*)d_in[3];
  const float* C1W = (const float*)d_in[4];
  const float* C1B = (const float*)d_in[5];
  const float* C1A = (const float*)d_in[6];
  const float* FW  = (const float*)d_in[7];
  const float* FB  = (const float*)d_in[8];
  const float* FA  = (const float*)d_in[9];
  const float* W2  = (const float*)d_in[10];
  const float* B2  = (const float*)d_in[11];
  const float* A2  = (const float*)d_in[12];
  const float* W3  = (const float*)d_in[13];
  const float* B3  = (const float*)d_in[14];
  const float* A3  = (const float*)d_in[15];
  const float* W4  = (const float*)d_in[16];
  const float* B4  = (const float*)d_in[17];
  const float* A4  = (const float*)d_in[18];
  const float* W5  = (const float*)d_in[19];
  const float* B5  = (const float*)d_in[20];
  float* OUT = (float*)d_out;
  (void)in_sizes; (void)n_in; (void)out_size; (void)ws_size;

  uint8_t* base = (uint8_t*)d_ws;
  size_t off = 0;
  auto alloc = [&](size_t bytes) -> uint8_t* {
    uint8_t* r = base + off;
    off += (bytes + 255) & ~(size_t)255;
    return r;
  };
  const size_t ACT_ELEMS = 4ull * PLANE16;             // 33,554,432 bf16
  short* act[3];
  for (int i = 0; i < 3; ++i) act[i] = (short*)alloc(ACT_ELEMS * 2);
  float* z_all = (float*)alloc(4194304ull * 4);
  float* s_all = (float*)alloc(53248ull * 4);
  short* wp234 = (short*)alloc(884736ull * 2);
  short* wpfus = (short*)alloc(516096ull * 2);

  k_pack<<<dim3(5472), dim3(256), 0, stream>>>(W2, W3, W4, FW, wp234, wpfus);
  k_sample<<<dim3(208), dim3(256), 0, stream>>>(X, SW, s_all);
  k_upz<<<dim3(16384), dim3(256), 0, stream>>>(s_all, UPW, UPB, z_all);

  int cur = 0, A = 1, B = 2;
  // head(0) -> cur
  k_conv1<<<dim3(2048), dim3(256), 0, stream>>>(z_all, C1W, C1B, C1A, act[cur]);

  for (int m = 0; m < 8; ++m) {
    const short* wp_t2 = wp234 + (0 * 8 + m) * 36864;
    const short* wp_t3 = wp234 + (1 * 8 + m) * 36864;
    const short* wp_t4 = wp234 + (2 * 8 + m) * 36864;

    k_conv<4><<<dim3(2048), dim3(512), 0, stream>>>(
        act[cur], act[cur], wp_t2, B2 + m * 64, A2 + m, act[A]);
    k_conv<4><<<dim3(2048), dim3(512), 0, stream>>>(
        act[A], act[A], wp_t3, B3 + m * 64, A3 + m, act[B]);
    k_conv<4><<<dim3(2048), dim3(512), 0, stream>>>(
        act[B], act[B], wp_t4, B4 + m * 64, A4 + m, act[A]);
    k_t5<<<dim3(2048), dim3(256), 0, stream>>>(
        act[A], W5 + m * 576, B5 + m, OUT + (size_t)m * 524288);

    if (m < 7) {
      // head(m+1) -> act[B] (free after t4 consumed it)
      k_conv1<<<dim3(2048), dim3(256), 0, stream>>>(
          z_all + (size_t)(m + 1) * 524288, C1W + (m + 1) * 576,
          C1B + (m + 1) * 64, C1A + (m + 1), act[B]);
      // fus(cur, head) -> act[A] (free after t5 consumed it)
      k_conv<8><<<dim3(2048), dim3(512), 0, stream>>>(
          act[cur], act[B], wpfus + m * 73728, FB + m * 64, FA + m, act[A]);
      int tmp = cur; cur = A; A = tmp;  // new cur = fus output
    }
  }
}